// Round 4
// baseline (1357.044 us; speedup 1.0000x reference)
//
#include <hip/hip_runtime.h>
#include <hip/hip_fp16.h>

// =====================================================================
// GCN pipeline on MI355X, round 4: de-serialized window kernel.
//  - fp16 feature tables (reference casts gathered feats to fp16 anyway)
//  - head-pair slabs: 2 gather phases instead of 4; ~10 barriers/block
//  - per-wave scores+softmax (wave = window x head, masked shuffles)
//  - hc (hoisted center path) stored fp16
// =====================================================================

typedef _Float16 half8v  __attribute__((ext_vector_type(8)));
typedef float    float4v __attribute__((ext_vector_type(4)));

// ---------------- workspace layout (bytes) ----------------
constexpr size_t OFF_S1a    = 0;
constexpr size_t OFF_S2a    = OFF_S1a + 64ull*2*256*4;
constexpr size_t OFF_S1b    = OFF_S2a + 64ull*2*256*4;
constexpr size_t OFF_S2b    = OFF_S1b + 64ull*2*512*4;
constexpr size_t OFF_S1f    = OFF_S2b + 64ull*2*512*4;
constexpr size_t OFF_S2f    = OFF_S1f + 64ull*2*256*4;
constexpr size_t STATS_BYTES= OFF_S2f + 64ull*2*256*4;      // zeroed each call
constexpr size_t OFF_MU1    = STATS_BYTES;
constexpr size_t OFF_RS1    = OFF_MU1 + 2048;
constexpr size_t OFF_MU2    = OFF_RS1 + 2048;
constexpr size_t OFF_RS2    = OFF_MU2 + 4096;
constexpr size_t OFF_MU3    = OFF_RS2 + 4096;
constexpr size_t OFF_RS3    = OFF_MU3 + 2048;
constexpr size_t OFF_MM     = OFF_RS3 + 2048;               // 12 floats
constexpr size_t OFF_KEYS   = OFF_MM + 256;
constexpr size_t OFF_INDS   = OFF_KEYS + 8ull*4096*8;
constexpr size_t OFF_PK6_1  = OFF_INDS + 8ull*4096*10*4;    // 1 MB
constexpr size_t OFF_PK6_2  = OFF_PK6_1 + 512ull*1024*2;    // 1 MB
constexpr size_t OFF_PK7_1  = OFF_PK6_2 + 512ull*1024*2;    // 256 KB
constexpr size_t OFF_PK7_2  = OFF_PK7_1 + 256ull*512*2;     // 512 KB
constexpr size_t OFF_WFOLD1 = OFF_PK7_2 + 512ull*512*2;
constexpr size_t OFF_WFOLD2 = OFF_WFOLD1 + 512ull*256*4;
constexpr size_t OFF_WCOMB1 = OFF_WFOLD2 + 512ull*256*4;
constexpr size_t OFF_WCOMB2 = OFF_WCOMB1 + 256ull*256*4;
constexpr size_t OFF_PC1    = OFF_WCOMB2 + 512ull*256*4;
constexpr size_t OFF_PC2    = OFF_PC1 + 256ull*256*2;
constexpr size_t OFF_BC1    = OFF_PC2 + 512ull*256*2;
constexpr size_t OFF_BC2    = OFF_BC1 + 1024;
constexpr size_t OFF_FEATST = OFF_BC2 + 2048;               // (B,N,256) fp16, 4 MB
constexpr size_t OFF_F1T    = OFF_FEATST + 2ull*4096*256*2; // (B,N,256) fp16
constexpr size_t OFF_F1N    = OFF_F1T   + 2ull*4096*256*2;  // (B,256,N) fp32, 8 MB
constexpr size_t OFF_F2N    = OFF_F1N   + 2ull*4096*256*4;  // (B,512,N) fp32, 16 MB
constexpr size_t OFF_HMAX1  = OFF_F2N   + 2ull*4096*512*4;  // 8 MB
constexpr size_t OFF_HMAX2  = OFF_HMAX1 + 2ull*4096*256*4;  // 16 MB
constexpr size_t OFF_HC1    = OFF_HMAX2 + 2ull*4096*512*4;  // fp16 4 MB
constexpr size_t OFF_HC2    = OFF_HC1   + 8192ull*256*2;    // fp16 8 MB
constexpr size_t WS_NEED    = OFF_HC2   + 8192ull*512*2;
constexpr size_t OFF_H3     = OFF_HMAX1;   // hmax1 dead after norm1

// ---------------- helpers ----------------
__device__ __forceinline__ int gcn_quant1(float c, float cmin, float scale) {
  float q = floorf(__fmul_rn(__fsub_rn(c, cmin), scale));
  q = fminf(fmaxf(q, 0.0f), 1023.0f);
  return (int)q;
}

__device__ __forceinline__ unsigned int gcn_morton3(int x, int y, int z) {
  unsigned int key = 0u;
#pragma unroll
  for (int b = 0; b < 10; ++b) {
    key |= ((unsigned)((x >> b) & 1)) << (3 * b + 2);
    key |= ((unsigned)((y >> b) & 1)) << (3 * b + 1);
    key |= ((unsigned)((z >> b) & 1)) << (3 * b + 0);
  }
  return key;
}

__device__ __forceinline__ unsigned int gcn_hilbert3(int x, int y, int z) {
  int X0 = x, X1 = y, X2 = z;
  for (int Q = 512; Q > 1; Q >>= 1) {
    int P = Q - 1;
    if (X0 & Q) X0 ^= P;
    {
      int t = (X0 ^ X1) & P;
      if (X1 & Q) { X0 ^= P; } else { X0 ^= t; X1 ^= t; }
    }
    {
      int t = (X0 ^ X2) & P;
      if (X2 & Q) { X0 ^= P; } else { X0 ^= t; X2 ^= t; }
    }
  }
  X1 ^= X0;
  X2 ^= X1;
  int t = 0;
  for (int Q = 512; Q > 1; Q >>= 1)
    if (X2 & Q) t ^= (Q - 1);
  X0 ^= t; X1 ^= t; X2 ^= t;
  unsigned int key = 0u;
#pragma unroll
  for (int b = 9; b >= 0; --b) {
    key = (key << 1) | (unsigned)((X0 >> b) & 1);
    key = (key << 1) | (unsigned)((X1 >> b) & 1);
    key = (key << 1) | (unsigned)((X2 >> b) & 1);
  }
  return key;
}

// ---------------- weight prep ----------------
__global__ void gcn_foldF(const float* __restrict__ W, float* __restrict__ Wf) {
  int i = blockIdx.x * 256 + threadIdx.x;   // 512*256
  int o = i >> 8, c = i & 255;
  float4 w = ((const float4*)W)[(size_t)o * 512 + c];
  Wf[i] = w.x + w.y + w.z + w.w;
}

__global__ void gcn_wcomb(const float* __restrict__ Wc, const float* __restrict__ blin,
                          const float* __restrict__ WfoldF, float* __restrict__ Wcomb,
                          float* __restrict__ bc) {
  __shared__ float wrow[512];
  int o2 = blockIdx.x, tid = threadIdx.x;
  wrow[tid] = Wc[(size_t)o2 * 512 + tid];
  wrow[tid + 256] = Wc[(size_t)o2 * 512 + tid + 256];
  __syncthreads();
  float acc = 0.f;
  for (int o = 0; o < 512; ++o)
    acc = fmaf(wrow[o], WfoldF[(size_t)o * 256 + tid], acc);
  Wcomb[(size_t)o2 * 256 + tid] = acc;
  if (tid == 0) {
    float s = 0.f;
    for (int o = 0; o < 512; ++o) s += wrow[o] * blin[o];
    bc[o2] = s;
  }
}

__global__ void gcn_packC(const float* __restrict__ Wcomb, _Float16* __restrict__ P) {
  int i = blockIdx.x * 256 + threadIdx.x;   // (O2/16)*8*64
  int lane = i & 63, ks = (i >> 6) & 7, nt = i >> 9;
  int tl = lane & 15, q = lane >> 4;
  int n = nt * 16 + tl;
  _Float16 tmp[8];
#pragma unroll
  for (int j = 0; j < 8; ++j)
    tmp[j] = (_Float16)Wcomb[(size_t)n * 256 + ks * 32 + q * 8 + j];
  *(half8v*)(P + (size_t)i * 8) = *(half8v*)tmp;
}

// P6 pack: k = hp*512 + m*128 + cl  ->  orig col 1024 + 4*(128*hp+cl) + m
__global__ void gcn_pack6(const float* __restrict__ W, _Float16* __restrict__ P) {
  int i = blockIdx.x * 256 + threadIdx.x;   // 65536
  int lane = i & 63, ks = (i >> 6) & 31, nt = i >> 11;
  int tl = lane & 15, q = lane >> 4;
  int o = nt * 16 + tl;
  _Float16 tmp[8];
#pragma unroll
  for (int j = 0; j < 8; ++j) {
    int k = ks * 32 + q * 8 + j;
    int hp = k >> 9, r = k & 511, m = r >> 7, cl = r & 127;
    int col = 1024 + 4 * (128 * hp + cl) + m;
    tmp[j] = (_Float16)W[(size_t)o * 2048 + col];
  }
  *(half8v*)(P + (size_t)i * 8) = *(half8v*)tmp;
}

__global__ void gcn_pack7(const float* __restrict__ W, _Float16* __restrict__ P) {
  int i = blockIdx.x * 256 + threadIdx.x;   // O2*64
  int lane = i & 63, ks = (i >> 6) & 15, nt = i >> 10;
  int tl = lane & 15, q = lane >> 4;
  int o2 = nt * 16 + tl;
  int c2 = ks * 32 + q * 8;
  _Float16 tmp[8];
#pragma unroll
  for (int j = 0; j < 8; ++j)
    tmp[j] = (_Float16)W[(size_t)o2 * 512 + c2 + j];
  *(half8v*)(P + (size_t)i * 8) = *(half8v*)tmp;
}

// ---------------- hc precompute (fp16 in / fp16 out) ----------------
template <int O2>
__global__ __launch_bounds__(256) void gcn_hc(const __half* __restrict__ src,
                                              const _Float16* __restrict__ PC,
                                              const float* __restrict__ bc,
                                              __half* __restrict__ out) {
  constexpr int NB = O2 / 64;
  __shared__ __align__(16) _Float16 As[64 * 264];
  int nb = blockIdx.x % NB, mb = blockIdx.x / NB;
  int tid = threadIdx.x;
  const __half2* s2 = (const __half2*)(src + (size_t)mb * 64 * 256);
  for (int idx = tid; idx < 64 * 128; idx += 256) {
    int row = idx >> 7, cp = idx & 127;
    __half2 v = s2[row * 128 + cp];
    *(__half2*)((char*)As + row * 528 + cp * 4) = v;
  }
  __syncthreads();
  int lane = tid & 63, w = tid >> 6, tl = lane & 15, q = lane >> 4;
  float4v acc[4];
#pragma unroll
  for (int t = 0; t < 4; ++t) acc[t] = (float4v){0.f, 0.f, 0.f, 0.f};
  const half8v* pc = (const half8v*)PC;
#pragma unroll
  for (int ks = 0; ks < 8; ++ks) {
    half8v a = *(const half8v*)((const char*)As + (w * 16 + tl) * 528 + ks * 64 + q * 16);
#pragma unroll
    for (int t = 0; t < 4; ++t) {
      half8v bf = pc[(size_t)(((nb * 4 + t) * 8 + ks)) * 64 + lane];
      acc[t] = __builtin_amdgcn_mfma_f32_16x16x32_f16(a, bf, acc[t], 0, 0, 0);
    }
  }
#pragma unroll
  for (int t = 0; t < 4; ++t) {
    int o = (nb * 4 + t) * 16 + tl;
    float bb = bc[o];
#pragma unroll
    for (int r = 0; r < 4; ++r) {
      int row = mb * 64 + w * 16 + q * 4 + r;
      out[(size_t)row * O2 + o] = __float2half(acc[t][r] + bb);
    }
  }
}

// ---------------- quantize prep ----------------
__global__ void gcn_minmax(const float* __restrict__ coords, float* __restrict__ mm) {
  __shared__ float slo[256], shi[256];
  int d = blockIdx.x, tid = threadIdx.x;
  float lo = 1e30f, hi = -1e30f;
  for (int i = tid; i < 4096; i += 256) {
    float v = coords[(size_t)d * 4096 + i];
    lo = fminf(lo, v);
    hi = fmaxf(hi, v);
  }
  slo[tid] = lo; shi[tid] = hi;
  __syncthreads();
  for (int s = 128; s > 0; s >>= 1) {
    if (tid < s) {
      slo[tid] = fminf(slo[tid], slo[tid + s]);
      shi[tid] = fmaxf(shi[tid], shi[tid + s]);
    }
    __syncthreads();
  }
  if (tid == 0) {
    mm[d] = slo[0];
    mm[6 + d] = 1023.0f / ((shi[0] - slo[0]) + 1e-6f);
  }
}

__global__ void gcn_keys(const float* __restrict__ coords, const float* __restrict__ mm,
                         unsigned long long* __restrict__ keys) {
  int idx = blockIdx.x * 256 + threadIdx.x;
  int b = idx >> 12, n = idx & 4095;
  const float* cb = coords + (size_t)b * 3 * 4096;
  int q0 = gcn_quant1(cb[n],        mm[b * 3 + 0], mm[6 + b * 3 + 0]);
  int q1 = gcn_quant1(cb[4096 + n], mm[b * 3 + 1], mm[6 + b * 3 + 1]);
  int q2 = gcn_quant1(cb[8192 + n], mm[b * 3 + 2], mm[6 + b * 3 + 2]);
  unsigned long long nn = (unsigned long long)(unsigned)n;
  size_t base = ((size_t)b * 4) * 4096 + n;
  keys[base]         = ((unsigned long long)gcn_morton3(q0, q1, q2) << 12) | nn;
  keys[base + 4096]  = ((unsigned long long)gcn_morton3(q1, q0, q2) << 12) | nn;
  keys[base + 8192]  = ((unsigned long long)gcn_hilbert3(q0, q1, q2) << 12) | nn;
  keys[base + 12288] = ((unsigned long long)gcn_hilbert3(q1, q0, q2) << 12) | nn;
}

// ---------------- bitonic sort (stable argsort replica) + windows ----------------
__global__ __launch_bounds__(1024) void gcn_sort(const unsigned long long* __restrict__ keys,
                                                 int* __restrict__ inds) {
  __shared__ unsigned long long a[4096];
  int g = blockIdx.x, tid = threadIdx.x;
  for (int i = tid; i < 4096; i += 1024) a[i] = keys[(size_t)g * 4096 + i];
  __syncthreads();
  for (int k = 2; k <= 4096; k <<= 1) {
    for (int j = k >> 1; j > 0; j >>= 1) {
      for (int t = tid; t < 2048; t += 1024) {
        int i = 2 * t - (t & (j - 1));
        int p = i + j;
        bool up = (i & k) == 0;
        unsigned long long x = a[i], y = a[p];
        if ((x > y) == up) { a[i] = y; a[p] = x; }
      }
      __syncthreads();
    }
  }
  for (int i = tid; i < 4096; i += 1024) {
    int start = i - 5; if (start < 0) start = 0;
    int endm1 = i + 5; if (endm1 > 4095) endm1 = 4095;
#pragma unroll
    for (int kk = 0; kk < 10; ++kk) {
      int pos = start + kk; if (pos > endm1) pos = endm1;
      inds[((size_t)g * 4096 + i) * 10 + kk] = (int)(a[pos] & 0xFFFULL);
    }
  }
}

// ---------------- transpose (B,C,N) fp32 -> (B,N,C) fp16 ----------------
__global__ void gcn_transpose(const float* __restrict__ feats, __half* __restrict__ fT) {
  __shared__ float t[32][33];
  int blk = blockIdx.x;
  int cb = blk & 7, nb = (blk >> 3) & 127, b = blk >> 10;
  int tx = threadIdx.x & 31, ty = threadIdx.x >> 5;
#pragma unroll
  for (int i = 0; i < 4; ++i) {
    int c = cb * 32 + ty + i * 8;
    t[ty + i * 8][tx] = feats[((size_t)(b * 256 + c) << 12) + nb * 32 + tx];
  }
  __syncthreads();
  if (tx < 16) {
#pragma unroll
    for (int i = 0; i < 4; ++i) {
      int nl = ty + i * 8;
      int n = nb * 32 + nl;
      __half2 hv = __floats2half2_rn(t[2 * tx][nl], t[2 * tx + 1][nl]);
      *(__half2*)(fT + ((size_t)((b << 12) + n)) * 256 + cb * 32 + 2 * tx) = hv;
    }
  }
}

// ---------------- fused 4-window MFMA kernel ----------------
// slab/FU: 48 rows x 1040 B at 0 (aliased in time); SC 800 f at 49920; IDX at 53120
constexpr int ROWB   = 1040;
constexpr int SM_SC  = 49920;
constexpr int SM_IDX = 53120;
constexpr int SM_TOT = 53760;

template <int O2>
__global__ __launch_bounds__(512, 6) void gcn_window(
    const __half* __restrict__ fT, const int* __restrict__ inds,
    const _Float16* __restrict__ PK6, const _Float16* __restrict__ PK7,
    const __half* __restrict__ hc,
    float* __restrict__ hmax, float* __restrict__ S1, float* __restrict__ S2,
    int p0, int p1, int p2, int p3) {
  __shared__ __align__(16) char smem[SM_TOT];
  float* sc  = (float*)(smem + SM_SC);
  int*   idx = (int*)(smem + SM_IDX);

  const int tid = threadIdx.x;
  const int lane = tid & 63, w = tid >> 6;
  const int tl = lane & 15, q = lane >> 4;
  const int b = blockIdx.x >> 10;
  const int n0 = (blockIdx.x & 1023) * 4;
  const __half* fTb = fT + ((size_t)(b << 12)) * 256;

  // stage window indices + zero garbage rows 40..47
  if (tid < 160) {
    int g = tid / 40, rem = tid % 40, m = rem / 10, kk = rem % 10;
    int meth = (m == 0) ? p0 : (m == 1) ? p1 : (m == 2) ? p2 : p3;
    idx[tid] = inds[((size_t)((b * 4 + meth) << 12) + n0 + g) * 10 + kk];
  }
  for (int i = tid; i < 2080; i += 512)
    ((int*)(smem + 40 * ROWB))[i] = 0;
  __syncthreads();

  float4v acc6[3][4];
#pragma unroll
  for (int mt = 0; mt < 3; ++mt)
#pragma unroll
    for (int t = 0; t < 4; ++t) acc6[mt][t] = (float4v){0.f, 0.f, 0.f, 0.f};

  const half8v* pk6 = (const half8v*)PK6;

#pragma unroll 1
  for (int hp = 0; hp < 2; ++hp) {
    // ---- P1: gather head-pair slab (128 fp16 cols), diff, layout d' = m*128+cl ----
#pragma unroll
    for (int s = 0; s < 2; ++s) {
      int slot = w * 2 + s;
      int g = slot >> 2, m = slot & 3;
      const __half2 cv = *(const __half2*)(fTb + (size_t)(n0 + g) * 256 + hp * 128 + 2 * lane);
      const int* ir = idx + (g * 4 + m) * 10;
#pragma unroll
      for (int kk = 0; kk < 10; ++kk) {
        __half2 v = *(const __half2*)(fTb + (size_t)ir[kk] * 256 + hp * 128 + 2 * lane);
        *(__half2*)(smem + (g * 10 + kk) * ROWB + m * 256 + lane * 4) = __hsub2(v, cv);
      }
    }
    __syncthreads();

    // ---- P2+P3: wave = (window g2, head hh); scores via MFMA + in-wave softmax ----
    {
      int g2 = w >> 1, hh = w & 1;
      float4v as = {0.f, 0.f, 0.f, 0.f};
      const char* rowbase = smem + (g2 * 10 + tl) * ROWB + hh * 128;
#pragma unroll
      for (int m4 = 0; m4 < 4; ++m4) {
        half8v a0 = *(const half8v*)(rowbase + m4 * 256 + q * 16);
        half8v a1 = *(const half8v*)(rowbase + m4 * 256 + 64 + q * 16);
        as = __builtin_amdgcn_mfma_f32_16x16x32_f16(a0, a0, as, 0, 0, 0);
        as = __builtin_amdgcn_mfma_f32_16x16x32_f16(a1, a1, as, 0, 0, 0);
      }
      bool vt = (tl < 10);
      float* scb = sc + (g2 * 2 + hh) * 100;
#pragma unroll
      for (int r = 0; r < 4; ++r) {
        float v = vt ? as[r] * 0.0625f : -1e30f;
        float m = v;
        m = fmaxf(m, __shfl_xor(m, 1));
        m = fmaxf(m, __shfl_xor(m, 2));
        m = fmaxf(m, __shfl_xor(m, 4));
        m = fmaxf(m, __shfl_xor(m, 8));
        float e = vt ? __expf(v - m) : 0.f;
        float su = e;
        su += __shfl_xor(su, 1);
        su += __shfl_xor(su, 2);
        su += __shfl_xor(su, 4);
        su += __shfl_xor(su, 8);
        float ar = e / su;
        int row = q * 4 + r;
        if (row < 10 && vt) scb[row * 10 + tl] = ar;
      }
    }
    __syncthreads();

    // ---- P4: out = attn @ x_diff, column-owned in place ----
    {
      int g4 = tid >> 7, cb2 = tid & 127;
#pragma unroll
      for (int hf = 0; hf < 2; ++hf) {
        int cc = cb2 + hf * 128;            // half2 index in [0,256)
        int hh = (cc & 63) >> 5;
        const float* arow = sc + (g4 * 2 + hh) * 100;
        __half2 xv[10];
#pragma unroll
        for (int j = 0; j < 10; ++j)
          xv[j] = *(const __half2*)(smem + (g4 * 10 + j) * ROWB + cc * 4);
#pragma unroll
        for (int kk = 0; kk < 10; ++kk) {
          float ax = 0.f, ay = 0.f;
#pragma unroll
          for (int j = 0; j < 10; ++j) {
            float wj = arow[kk * 10 + j];
            float2 f = __half22float2(xv[j]);
            ax = fmaf(wj, f.x, ax);
            ay = fmaf(wj, f.y, ay);
          }
          *(__half2*)(smem + (g4 * 10 + kk) * ROWB + cc * 4) = __floats2half2_rn(ax, ay);
        }
      }
    }
    __syncthreads();

    // ---- P6 partial: acc6 += out_slab @ Wd_slab^T ----
#pragma unroll 2
    for (int ks = 0; ks < 16; ++ks) {
      half8v a0 = *(const half8v*)(smem + (0  + tl) * ROWB + ks * 64 + q * 16);
      half8v a1 = *(const half8v*)(smem + (16 + tl) * ROWB + ks * 64 + q * 16);
      half8v a2 = *(const half8v*)(smem + (32 + tl) * ROWB + ks * 64 + q * 16);
#pragma unroll
      for (int t = 0; t < 4; ++t) {
        half8v bf = pk6[(size_t)(((w * 4 + t) * 32 + hp * 16 + ks)) * 64 + lane];
        acc6[0][t] = __builtin_amdgcn_mfma_f32_16x16x32_f16(a0, bf, acc6[0][t], 0, 0, 0);
        acc6[1][t] = __builtin_amdgcn_mfma_f32_16x16x32_f16(a1, bf, acc6[1][t], 0, 0, 0);
        acc6[2][t] = __builtin_amdgcn_mfma_f32_16x16x32_f16(a2, bf, acc6[2][t], 0, 0, 0);
      }
    }
    __syncthreads();
  }

  // ---- FU write (aliases slab; all P6 reads done) ----
#pragma unroll
  for (int mt = 0; mt < 3; ++mt)
#pragma unroll
    for (int t = 0; t < 4; ++t) {
      int o = (w * 4 + t) * 16 + tl;
#pragma unroll
      for (int r = 0; r < 4; ++r) {
        int row = 16 * mt + q * 4 + r;
        *(__half*)(smem + row * ROWB + o * 2) = __float2half(acc6[mt][t][r]);
      }
    }
  __syncthreads();

  // ---- P7: h = fused @ Wc^T + hc, then max_k + stats ----
  {
    constexpr int NT = O2 / 128;
    float4v acc7[3][NT];
#pragma unroll
    for (int mt = 0; mt < 3; ++mt)
#pragma unroll
      for (int t = 0; t < NT; ++t) acc7[mt][t] = (float4v){0.f, 0.f, 0.f, 0.f};
    const half8v* pk7 = (const half8v*)PK7;
#pragma unroll 2
    for (int ks = 0; ks < 16; ++ks) {
      half8v a0 = *(const half8v*)(smem + (0  + tl) * ROWB + ks * 64 + q * 16);
      half8v a1 = *(const half8v*)(smem + (16 + tl) * ROWB + ks * 64 + q * 16);
      half8v a2 = *(const half8v*)(smem + (32 + tl) * ROWB + ks * 64 + q * 16);
#pragma unroll
      for (int t = 0; t < NT; ++t) {
        half8v bf = pk7[(size_t)(((w * NT + t) * 16 + ks)) * 64 + lane];
        acc7[0][t] = __builtin_amdgcn_mfma_f32_16x16x32_f16(a0, bf, acc7[0][t], 0, 0, 0);
        acc7[1][t] = __builtin_amdgcn_mfma_f32_16x16x32_f16(a1, bf, acc7[1][t], 0, 0, 0);
        acc7[2][t] = __builtin_amdgcn_mfma_f32_16x16x32_f16(a2, bf, acc7[2][t], 0, 0, 0);
      }
    }
    const int slot = blockIdx.x & 63;
#pragma unroll
    for (int t = 0; t < NT; ++t) {
      int o2 = (w * NT + t) * 16 + tl;
      float hcv[4], mx[4], s1[4], s2[4];
#pragma unroll
      for (int g = 0; g < 4; ++g) {
        hcv[g] = __half2float(hc[((size_t)((b << 12) + n0 + g)) * O2 + o2]);
        mx[g] = -1e30f; s1[g] = 0.f; s2[g] = 0.f;
      }
#pragma unroll
      for (int mt = 0; mt < 3; ++mt)
#pragma unroll
        for (int r = 0; r < 4; ++r) {
          int gr = 16 * mt + 4 * q + r;
#pragma unroll
          for (int g = 0; g < 4; ++g) {
            if (gr >= 10 * g && gr < 10 * g + 10) {
              float v = acc7[mt][t][r] + hcv[g];
              mx[g] = fmaxf(mx[g], v);
              s1[g] += v;
              s2[g] = fmaf(v, v, s2[g]);
            }
          }
        }
#pragma unroll
      for (int g = 0; g < 4; ++g) {
        mx[g] = fmaxf(mx[g], __shfl_xor(mx[g], 16));
        mx[g] = fmaxf(mx[g], __shfl_xor(mx[g], 32));
      }
      float s1t = (s1[0] + s1[1]) + (s1[2] + s1[3]);
      float s2t = (s2[0] + s2[1]) + (s2[2] + s2[3]);
      s1t += __shfl_xor(s1t, 16); s1t += __shfl_xor(s1t, 32);
      s2t += __shfl_xor(s2t, 16); s2t += __shfl_xor(s2t, 32);
      if (q == 0) {
        float4 mv = make_float4(mx[0], mx[1], mx[2], mx[3]);
        *(float4*)(hmax + (((size_t)(b * O2 + o2)) << 12) + n0) = mv;
        atomicAdd(&S1[(size_t)(slot * 2 + b) * O2 + o2], s1t);
        atomicAdd(&S2[(size_t)(slot * 2 + b) * O2 + o2], s2t);
      }
    }
  }
}

// ---------------- stats reduce ----------------
__global__ void gcn_stats(const float* __restrict__ S1, const float* __restrict__ S2,
                          float* __restrict__ mu, float* __restrict__ rs,
                          int O2, float invNK) {
  int t = threadIdx.x;
  if (t < 2 * O2) {
    float s1 = 0.f, s2 = 0.f;
    for (int s = 0; s < 64; ++s) {
      s1 += S1[(size_t)s * 2 * O2 + t];
      s2 += S2[(size_t)s * 2 * O2 + t];
    }
    float m = s1 * invNK;
    float var = s2 * invNK - m * m;
    mu[t] = m;
    rs[t] = 1.0f / sqrtf(var + 1e-5f);
  }
}

// ---------------- normalize + lrelu; optional fp16 transposed copy ----------------
__global__ void gcn_norm(const float* __restrict__ src, const float* __restrict__ mu,
                         const float* __restrict__ rs, float* __restrict__ fN,
                         __half* __restrict__ fT16) {
  int idx = blockIdx.x * 256 + threadIdx.x;
  int n = idx & 4095;
  int bo = idx >> 12;
  float v = (src[idx] - mu[bo]) * rs[bo];
  v = v > 0.f ? v : 0.2f * v;
  fN[idx] = v;
  if (fT16 != nullptr) {
    int o = bo & 255;
    int b = bo >> 8;
    fT16[((size_t)((b << 12) + n)) * 256 + o] = __float2half(v);
  }
}

// ---------------- final conv (fp32 VALU) ----------------
__global__ __launch_bounds__(256, 2) void gcn_final_conv(
    const float* __restrict__ feats, const float* __restrict__ f1N,
    const float* __restrict__ f2N, const float* __restrict__ Wc3,
    float* __restrict__ h3, float* __restrict__ S1, float* __restrict__ S2) {
  __shared__ float ftile[128 * 64];
  int x = blockIdx.x;
  int ob = x & 3, nb = (x >> 2) & 63, b = x >> 8;
  int lane = threadIdx.x & 63, wave = threadIdx.x >> 6;
  int n0 = nb * 64, o0 = ob * 64;
  float acc[16];
#pragma unroll
  for (int i = 0; i < 16; ++i) acc[i] = 0.f;
  for (int ct = 0; ct < 8; ++ct) {
    int cg0 = ct * 128;
    __syncthreads();
    for (int idx = threadIdx.x; idx < 8192; idx += 256) {
      int ccc = idx >> 6, ln = idx & 63;
      int c = cg0 + ccc;
      float v;
      if (c < 256)      v = feats[((size_t)(b * 256 + c) << 12) + n0 + ln];
      else if (c < 512) v = f1N[((size_t)(b * 256 + (c - 256)) << 12) + n0 + ln];
      else              v = f2N[((size_t)(b * 512 + (c - 512)) << 12) + n0 + ln];
      ftile[ccc * 64 + ln] = v;
    }
    __syncthreads();
    for (int c = 0; c < 128; ++c) {
      float fv = ftile[c * 64 + lane];
#pragma unroll
      for (int oi = 0; oi < 16; ++oi) {
        int o = o0 + wave * 16 + oi;
        acc[oi] = fmaf(Wc3[(size_t)o * 1024 + cg0 + c], fv, acc[oi]);
      }
    }
  }
  int slot = nb;
#pragma unroll
  for (int oi = 0; oi < 16; ++oi) {
    int o = o0 + wave * 16 + oi;
    float v = acc[oi];
    h3[((size_t)(b * 256 + o) << 12) + n0 + lane] = v;
    float s1 = v, s2 = v * v;
#pragma unroll
    for (int m = 1; m < 64; m <<= 1) {
      s1 += __shfl_xor(s1, m);
      s2 += __shfl_xor(s2, m);
    }
    if (lane == 0) {
      atomicAdd(&S1[(size_t)(slot * 2 + b) * 256 + o], s1);
      atomicAdd(&S2[(size_t)(slot * 2 + b) * 256 + o], s2);
    }
  }
}

// ---------------- launch ----------------
extern "C" void kernel_launch(void* const* d_in, const int* in_sizes, int n_in,
                              void* d_out, int out_size, void* d_ws, size_t ws_size,
                              hipStream_t stream) {
  (void)in_sizes; (void)n_in; (void)out_size; (void)ws_size;
  const float* coords  = (const float*)d_in[0];
  const float* feats   = (const float*)d_in[1];
  const float* W_lin1  = (const float*)d_in[2];
  const float* b_lin1  = (const float*)d_in[3];
  const float* W_lin2  = (const float*)d_in[4];
  const float* b_lin2  = (const float*)d_in[5];
  const float* W_conv1 = (const float*)d_in[6];
  const float* W_conv2 = (const float*)d_in[7];
  const float* W_conv3 = (const float*)d_in[8];
  char* ws = (char*)d_ws;

  float* F_MM    = (float*)(ws + OFF_MM);
  unsigned long long* KEYS = (unsigned long long*)(ws + OFF_KEYS);
  int* INDS      = (int*)(ws + OFF_INDS);
  _Float16* PK61 = (_Float16*)(ws + OFF_PK6_1);
  _Float16* PK62 = (_Float16*)(ws + OFF_PK6_2);
  _Float16* PK71 = (_Float16*)(ws + OFF_PK7_1);
  _Float16* PK72 = (_Float16*)(ws + OFF_PK7_2);
  float* WFOLD1  = (float*)(ws + OFF_WFOLD1);
  float* WFOLD2  = (float*)(ws + OFF_WFOLD2);
  float* WCOMB1  = (float*)(ws + OFF_WCOMB1);
  float* WCOMB2  = (float*)(ws + OFF_WCOMB2);
  _Float16* PC1  = (_Float16*)(ws + OFF_PC1);
  _Float16* PC2  = (_Float16*)(ws + OFF_PC2);
  float* BC1     = (float*)(ws + OFF_BC1);
  float* BC2     = (float*)(ws + OFF_BC2);
  __half* FEATST = (__half*)(ws + OFF_FEATST);
  __half* F1T    = (__half*)(ws + OFF_F1T);
  float* F1N     = (float*)(ws + OFF_F1N);
  float* F2N     = (float*)(ws + OFF_F2N);
  float* HMAX1   = (float*)(ws + OFF_HMAX1);
  float* HMAX2   = (float*)(ws + OFF_HMAX2);
  __half* HC1    = (__half*)(ws + OFF_HC1);
  __half* HC2    = (__half*)(ws + OFF_HC2);
  float* H3      = (float*)(ws + OFF_H3);

  (void)hipMemsetAsync(ws + OFF_S1a, 0, STATS_BYTES, stream);

  // weight prep
  gcn_foldF<<<512, 256, 0, stream>>>(W_lin1, WFOLD1);
  gcn_foldF<<<512, 256, 0, stream>>>(W_lin2, WFOLD2);
  gcn_wcomb<<<256, 256, 0, stream>>>(W_conv1, b_lin1, WFOLD1, WCOMB1, BC1);
  gcn_wcomb<<<512, 256, 0, stream>>>(W_conv2, b_lin2, WFOLD2, WCOMB2, BC2);
  gcn_packC<<<32, 256, 0, stream>>>(WCOMB1, PC1);
  gcn_packC<<<64, 256, 0, stream>>>(WCOMB2, PC2);
  gcn_pack6<<<256, 256, 0, stream>>>(W_lin1, PK61);
  gcn_pack6<<<256, 256, 0, stream>>>(W_lin2, PK62);
  gcn_pack7<<<64,  256, 0, stream>>>(W_conv1, PK71);
  gcn_pack7<<<128, 256, 0, stream>>>(W_conv2, PK72);

  // keys + sort + transpose
  gcn_minmax<<<6, 256, 0, stream>>>(coords, F_MM);
  gcn_keys<<<32, 256, 0, stream>>>(coords, F_MM, KEYS);
  gcn_sort<<<8, 1024, 0, stream>>>(KEYS, INDS);
  gcn_transpose<<<2048, 256, 0, stream>>>(feats, FEATST);

  // layer 1 (perm1 = [2,0,3,1])
  gcn_hc<256><<<512, 256, 0, stream>>>(FEATST, PC1, BC1, HC1);
  gcn_window<256><<<2048, 512, 0, stream>>>(
      FEATST, INDS, PK61, PK71, HC1,
      HMAX1, (float*)(ws + OFF_S1a), (float*)(ws + OFF_S2a), 2, 0, 3, 1);
  gcn_stats<<<1, 1024, 0, stream>>>((float*)(ws + OFF_S1a), (float*)(ws + OFF_S2a),
                                    (float*)(ws + OFF_MU1), (float*)(ws + OFF_RS1),
                                    256, 1.0f / 40960.0f);
  gcn_norm<<<8192, 256, 0, stream>>>(HMAX1, (float*)(ws + OFF_MU1), (float*)(ws + OFF_RS1),
                                     F1N, F1T);

  // layer 2 (perm2 = [1,3,0,2])
  gcn_hc<512><<<1024, 256, 0, stream>>>(F1T, PC2, BC2, HC2);
  gcn_window<512><<<2048, 512, 0, stream>>>(
      F1T, INDS, PK62, PK72, HC2,
      HMAX2, (float*)(ws + OFF_S1b), (float*)(ws + OFF_S2b), 1, 3, 0, 2);
  gcn_stats<<<1, 1024, 0, stream>>>((float*)(ws + OFF_S1b), (float*)(ws + OFF_S2b),
                                    (float*)(ws + OFF_MU2), (float*)(ws + OFF_RS2),
                                    512, 1.0f / 40960.0f);
  gcn_norm<<<16384, 256, 0, stream>>>(HMAX2, (float*)(ws + OFF_MU2), (float*)(ws + OFF_RS2),
                                      F2N, nullptr);

  // final conv + norm
  gcn_final_conv<<<512, 256, 0, stream>>>(feats, F1N, F2N, W_conv3,
                                          H3, (float*)(ws + OFF_S1f), (float*)(ws + OFF_S2f));
  gcn_stats<<<1, 1024, 0, stream>>>((float*)(ws + OFF_S1f), (float*)(ws + OFF_S2f),
                                    (float*)(ws + OFF_MU3), (float*)(ws + OFF_RS3),
                                    256, 1.0f / 4096.0f);
  gcn_norm<<<8192, 256, 0, stream>>>(H3, (float*)(ws + OFF_MU3), (float*)(ws + OFF_RS3),
                                     (float*)d_out, nullptr);
}

// Round 5
// 1118.769 us; speedup vs baseline: 1.2130x; 1.2130x over previous
//
#include <hip/hip_runtime.h>
#include <hip/hip_fp16.h>

// =====================================================================
// GCN pipeline on MI355X, round 5:
//  - launch_bounds (512,4): undo r4's VGPR cap (spill-to-scratch caused
//    +300 MB WRITE_SIZE and the r4 regression)
//  - atomic-free stats: per-block slot stores + gcn_stats2 reduction
//  - hmax in [b][n][O2] (coalesced); norm writes fp16 [n][c] tables only
//  - final_conv reads f1/f2 fp16 [n][c] via padded LDS transpose tile
// =====================================================================

typedef _Float16 half8v  __attribute__((ext_vector_type(8)));
typedef float    float4v __attribute__((ext_vector_type(4)));

// ---------------- workspace layout (bytes) ----------------
constexpr size_t OFF_S1f    = 0;                            // 64 slots*2*256 f
constexpr size_t OFF_S2f    = OFF_S1f + 64ull*2*256*4;
constexpr size_t STATSF_B   = OFF_S2f + 64ull*2*256*4;      // memset region (256 KB)
constexpr size_t OFF_MU1    = STATSF_B;
constexpr size_t OFF_RS1    = OFF_MU1 + 2048;
constexpr size_t OFF_MU2    = OFF_RS1 + 2048;
constexpr size_t OFF_RS2    = OFF_MU2 + 4096;
constexpr size_t OFF_MU3    = OFF_RS2 + 4096;
constexpr size_t OFF_RS3    = OFF_MU3 + 2048;
constexpr size_t OFF_MM     = OFF_RS3 + 2048;               // 12 floats
constexpr size_t OFF_KEYS   = OFF_MM + 256;
constexpr size_t OFF_INDS   = OFF_KEYS + 8ull*4096*8;
constexpr size_t OFF_PK6_1  = OFF_INDS + 8ull*4096*10*4;    // 1 MB
constexpr size_t OFF_PK6_2  = OFF_PK6_1 + 512ull*1024*2;
constexpr size_t OFF_PK7_1  = OFF_PK6_2 + 512ull*1024*2;
constexpr size_t OFF_PK7_2  = OFF_PK7_1 + 256ull*512*2;
constexpr size_t OFF_WFOLD1 = OFF_PK7_2 + 512ull*512*2;
constexpr size_t OFF_WFOLD2 = OFF_WFOLD1 + 512ull*256*4;
constexpr size_t OFF_WCOMB1 = OFF_WFOLD2 + 512ull*256*4;
constexpr size_t OFF_WCOMB2 = OFF_WCOMB1 + 256ull*256*4;
constexpr size_t OFF_PC1    = OFF_WCOMB2 + 512ull*256*4;
constexpr size_t OFF_PC2    = OFF_PC1 + 256ull*256*2;
constexpr size_t OFF_BC1    = OFF_PC2 + 512ull*256*2;
constexpr size_t OFF_BC2    = OFF_BC1 + 1024;
constexpr size_t OFF_FEATST = OFF_BC2 + 2048;               // (B,N,256) fp16
constexpr size_t OFF_F1T    = OFF_FEATST + 2ull*4096*256*2; // (B,N,256) fp16
constexpr size_t OFF_F2T    = OFF_F1T   + 2ull*4096*256*2;  // (B,N,512) fp16
constexpr size_t OFF_HMAX1  = OFF_F2T   + 2ull*4096*512*2;  // (B,N,256) fp32
constexpr size_t OFF_HMAX2  = OFF_HMAX1 + 2ull*4096*256*4;  // (B,N,512) fp32
constexpr size_t OFF_HC1    = OFF_HMAX2 + 2ull*4096*512*4;  // fp16 (B*N,256)
constexpr size_t OFF_HC2    = OFF_HC1   + 8192ull*256*2;    // fp16 (B*N,512)
constexpr size_t OFF_S1W    = OFF_HC2   + 8192ull*512*2;    // [2048][<=512] f
constexpr size_t OFF_S2W    = OFF_S1W   + 2048ull*512*4;
constexpr size_t WS_NEED    = OFF_S2W   + 2048ull*512*4;
// lifetime-disjoint alias: H3 [b][256][n] fp32, written by final_conv after
// HMAX1 was consumed by norm16-L1.
constexpr size_t OFF_H3     = OFF_HMAX1;

// ---------------- helpers ----------------
__device__ __forceinline__ int gcn_quant1(float c, float cmin, float scale) {
  float q = floorf(__fmul_rn(__fsub_rn(c, cmin), scale));
  q = fminf(fmaxf(q, 0.0f), 1023.0f);
  return (int)q;
}

__device__ __forceinline__ unsigned int gcn_morton3(int x, int y, int z) {
  unsigned int key = 0u;
#pragma unroll
  for (int b = 0; b < 10; ++b) {
    key |= ((unsigned)((x >> b) & 1)) << (3 * b + 2);
    key |= ((unsigned)((y >> b) & 1)) << (3 * b + 1);
    key |= ((unsigned)((z >> b) & 1)) << (3 * b + 0);
  }
  return key;
}

__device__ __forceinline__ unsigned int gcn_hilbert3(int x, int y, int z) {
  int X0 = x, X1 = y, X2 = z;
  for (int Q = 512; Q > 1; Q >>= 1) {
    int P = Q - 1;
    if (X0 & Q) X0 ^= P;
    {
      int t = (X0 ^ X1) & P;
      if (X1 & Q) { X0 ^= P; } else { X0 ^= t; X1 ^= t; }
    }
    {
      int t = (X0 ^ X2) & P;
      if (X2 & Q) { X0 ^= P; } else { X0 ^= t; X2 ^= t; }
    }
  }
  X1 ^= X0;
  X2 ^= X1;
  int t = 0;
  for (int Q = 512; Q > 1; Q >>= 1)
    if (X2 & Q) t ^= (Q - 1);
  X0 ^= t; X1 ^= t; X2 ^= t;
  unsigned int key = 0u;
#pragma unroll
  for (int b = 9; b >= 0; --b) {
    key = (key << 1) | (unsigned)((X0 >> b) & 1);
    key = (key << 1) | (unsigned)((X1 >> b) & 1);
    key = (key << 1) | (unsigned)((X2 >> b) & 1);
  }
  return key;
}

// ---------------- weight prep ----------------
__global__ void gcn_foldF(const float* __restrict__ W, float* __restrict__ Wf) {
  int i = blockIdx.x * 256 + threadIdx.x;   // 512*256
  int o = i >> 8, c = i & 255;
  float4 w = ((const float4*)W)[(size_t)o * 512 + c];
  Wf[i] = w.x + w.y + w.z + w.w;
}

__global__ void gcn_wcomb(const float* __restrict__ Wc, const float* __restrict__ blin,
                          const float* __restrict__ WfoldF, float* __restrict__ Wcomb,
                          float* __restrict__ bc) {
  __shared__ float wrow[512];
  int o2 = blockIdx.x, tid = threadIdx.x;
  wrow[tid] = Wc[(size_t)o2 * 512 + tid];
  wrow[tid + 256] = Wc[(size_t)o2 * 512 + tid + 256];
  __syncthreads();
  float acc = 0.f;
  for (int o = 0; o < 512; ++o)
    acc = fmaf(wrow[o], WfoldF[(size_t)o * 256 + tid], acc);
  Wcomb[(size_t)o2 * 256 + tid] = acc;
  if (tid == 0) {
    float s = 0.f;
    for (int o = 0; o < 512; ++o) s += wrow[o] * blin[o];
    bc[o2] = s;
  }
}

__global__ void gcn_packC(const float* __restrict__ Wcomb, _Float16* __restrict__ P) {
  int i = blockIdx.x * 256 + threadIdx.x;   // (O2/16)*8*64
  int lane = i & 63, ks = (i >> 6) & 7, nt = i >> 9;
  int tl = lane & 15, q = lane >> 4;
  int n = nt * 16 + tl;
  _Float16 tmp[8];
#pragma unroll
  for (int j = 0; j < 8; ++j)
    tmp[j] = (_Float16)Wcomb[(size_t)n * 256 + ks * 32 + q * 8 + j];
  *(half8v*)(P + (size_t)i * 8) = *(half8v*)tmp;
}

// P6 pack: k = hp*512 + m*128 + cl  ->  orig col 1024 + 4*(128*hp+cl) + m
__global__ void gcn_pack6(const float* __restrict__ W, _Float16* __restrict__ P) {
  int i = blockIdx.x * 256 + threadIdx.x;   // 65536
  int lane = i & 63, ks = (i >> 6) & 31, nt = i >> 11;
  int tl = lane & 15, q = lane >> 4;
  int o = nt * 16 + tl;
  _Float16 tmp[8];
#pragma unroll
  for (int j = 0; j < 8; ++j) {
    int k = ks * 32 + q * 8 + j;
    int hp = k >> 9, r = k & 511, m = r >> 7, cl = r & 127;
    int col = 1024 + 4 * (128 * hp + cl) + m;
    tmp[j] = (_Float16)W[(size_t)o * 2048 + col];
  }
  *(half8v*)(P + (size_t)i * 8) = *(half8v*)tmp;
}

__global__ void gcn_pack7(const float* __restrict__ W, _Float16* __restrict__ P) {
  int i = blockIdx.x * 256 + threadIdx.x;   // O2*64
  int lane = i & 63, ks = (i >> 6) & 15, nt = i >> 10;
  int tl = lane & 15, q = lane >> 4;
  int o2 = nt * 16 + tl;
  int c2 = ks * 32 + q * 8;
  _Float16 tmp[8];
#pragma unroll
  for (int j = 0; j < 8; ++j)
    tmp[j] = (_Float16)W[(size_t)o2 * 512 + c2 + j];
  *(half8v*)(P + (size_t)i * 8) = *(half8v*)tmp;
}

// ---------------- hc precompute (fp16 in / fp16 out) ----------------
template <int O2>
__global__ __launch_bounds__(256) void gcn_hc(const __half* __restrict__ src,
                                              const _Float16* __restrict__ PC,
                                              const float* __restrict__ bc,
                                              __half* __restrict__ out) {
  constexpr int NB = O2 / 64;
  __shared__ __align__(16) _Float16 As[64 * 264];
  int nb = blockIdx.x % NB, mb = blockIdx.x / NB;
  int tid = threadIdx.x;
  const __half2* s2 = (const __half2*)(src + (size_t)mb * 64 * 256);
  for (int idx = tid; idx < 64 * 128; idx += 256) {
    int row = idx >> 7, cp = idx & 127;
    __half2 v = s2[row * 128 + cp];
    *(__half2*)((char*)As + row * 528 + cp * 4) = v;
  }
  __syncthreads();
  int lane = tid & 63, w = tid >> 6, tl = lane & 15, q = lane >> 4;
  float4v acc[4];
#pragma unroll
  for (int t = 0; t < 4; ++t) acc[t] = (float4v){0.f, 0.f, 0.f, 0.f};
  const half8v* pc = (const half8v*)PC;
#pragma unroll
  for (int ks = 0; ks < 8; ++ks) {
    half8v a = *(const half8v*)((const char*)As + (w * 16 + tl) * 528 + ks * 64 + q * 16);
#pragma unroll
    for (int t = 0; t < 4; ++t) {
      half8v bf = pc[(size_t)(((nb * 4 + t) * 8 + ks)) * 64 + lane];
      acc[t] = __builtin_amdgcn_mfma_f32_16x16x32_f16(a, bf, acc[t], 0, 0, 0);
    }
  }
#pragma unroll
  for (int t = 0; t < 4; ++t) {
    int o = (nb * 4 + t) * 16 + tl;
    float bb = bc[o];
#pragma unroll
    for (int r = 0; r < 4; ++r) {
      int row = mb * 64 + w * 16 + q * 4 + r;
      out[(size_t)row * O2 + o] = __float2half(acc[t][r] + bb);
    }
  }
}

// ---------------- quantize prep ----------------
__global__ void gcn_minmax(const float* __restrict__ coords, float* __restrict__ mm) {
  __shared__ float slo[256], shi[256];
  int d = blockIdx.x, tid = threadIdx.x;
  float lo = 1e30f, hi = -1e30f;
  for (int i = tid; i < 4096; i += 256) {
    float v = coords[(size_t)d * 4096 + i];
    lo = fminf(lo, v);
    hi = fmaxf(hi, v);
  }
  slo[tid] = lo; shi[tid] = hi;
  __syncthreads();
  for (int s = 128; s > 0; s >>= 1) {
    if (tid < s) {
      slo[tid] = fminf(slo[tid], slo[tid + s]);
      shi[tid] = fmaxf(shi[tid], shi[tid + s]);
    }
    __syncthreads();
  }
  if (tid == 0) {
    mm[d] = slo[0];
    mm[6 + d] = 1023.0f / ((shi[0] - slo[0]) + 1e-6f);
  }
}

__global__ void gcn_keys(const float* __restrict__ coords, const float* __restrict__ mm,
                         unsigned long long* __restrict__ keys) {
  int idx = blockIdx.x * 256 + threadIdx.x;
  int b = idx >> 12, n = idx & 4095;
  const float* cb = coords + (size_t)b * 3 * 4096;
  int q0 = gcn_quant1(cb[n],        mm[b * 3 + 0], mm[6 + b * 3 + 0]);
  int q1 = gcn_quant1(cb[4096 + n], mm[b * 3 + 1], mm[6 + b * 3 + 1]);
  int q2 = gcn_quant1(cb[8192 + n], mm[b * 3 + 2], mm[6 + b * 3 + 2]);
  unsigned long long nn = (unsigned long long)(unsigned)n;
  size_t base = ((size_t)b * 4) * 4096 + n;
  keys[base]         = ((unsigned long long)gcn_morton3(q0, q1, q2) << 12) | nn;
  keys[base + 4096]  = ((unsigned long long)gcn_morton3(q1, q0, q2) << 12) | nn;
  keys[base + 8192]  = ((unsigned long long)gcn_hilbert3(q0, q1, q2) << 12) | nn;
  keys[base + 12288] = ((unsigned long long)gcn_hilbert3(q1, q0, q2) << 12) | nn;
}

// ---------------- bitonic sort (stable argsort replica) + windows ----------------
__global__ __launch_bounds__(1024) void gcn_sort(const unsigned long long* __restrict__ keys,
                                                 int* __restrict__ inds) {
  __shared__ unsigned long long a[4096];
  int g = blockIdx.x, tid = threadIdx.x;
  for (int i = tid; i < 4096; i += 1024) a[i] = keys[(size_t)g * 4096 + i];
  __syncthreads();
  for (int k = 2; k <= 4096; k <<= 1) {
    for (int j = k >> 1; j > 0; j >>= 1) {
      for (int t = tid; t < 2048; t += 1024) {
        int i = 2 * t - (t & (j - 1));
        int p = i + j;
        bool up = (i & k) == 0;
        unsigned long long x = a[i], y = a[p];
        if ((x > y) == up) { a[i] = y; a[p] = x; }
      }
      __syncthreads();
    }
  }
  for (int i = tid; i < 4096; i += 1024) {
    int start = i - 5; if (start < 0) start = 0;
    int endm1 = i + 5; if (endm1 > 4095) endm1 = 4095;
#pragma unroll
    for (int kk = 0; kk < 10; ++kk) {
      int pos = start + kk; if (pos > endm1) pos = endm1;
      inds[((size_t)g * 4096 + i) * 10 + kk] = (int)(a[pos] & 0xFFFULL);
    }
  }
}

// ---------------- transpose (B,C,N) fp32 -> (B,N,C) fp16 ----------------
__global__ void gcn_transpose(const float* __restrict__ feats, __half* __restrict__ fT) {
  __shared__ float t[32][33];
  int blk = blockIdx.x;
  int cb = blk & 7, nb = (blk >> 3) & 127, b = blk >> 10;
  int tx = threadIdx.x & 31, ty = threadIdx.x >> 5;
#pragma unroll
  for (int i = 0; i < 4; ++i) {
    int c = cb * 32 + ty + i * 8;
    t[ty + i * 8][tx] = feats[((size_t)(b * 256 + c) << 12) + nb * 32 + tx];
  }
  __syncthreads();
  if (tx < 16) {
#pragma unroll
    for (int i = 0; i < 4; ++i) {
      int nl = ty + i * 8;
      int n = nb * 32 + nl;
      __half2 hv = __floats2half2_rn(t[2 * tx][nl], t[2 * tx + 1][nl]);
      *(__half2*)(fT + ((size_t)((b << 12) + n)) * 256 + cb * 32 + 2 * tx) = hv;
    }
  }
}

// ---------------- fused 4-window MFMA kernel ----------------
// slab/FU: 48 rows x 1040 B at 0 (aliased in time); SC 800 f at 49920; IDX at 53120
constexpr int ROWB   = 1040;
constexpr int SM_SC  = 49920;
constexpr int SM_IDX = 53120;
constexpr int SM_TOT = 53760;

template <int O2>
__global__ __launch_bounds__(512, 4) void gcn_window(
    const __half* __restrict__ fT, const int* __restrict__ inds,
    const _Float16* __restrict__ PK6, const _Float16* __restrict__ PK7,
    const __half* __restrict__ hc,
    float* __restrict__ hmax, float* __restrict__ S1, float* __restrict__ S2,
    int p0, int p1, int p2, int p3) {
  __shared__ __align__(16) char smem[SM_TOT];
  float* sc  = (float*)(smem + SM_SC);
  int*   idx = (int*)(smem + SM_IDX);

  const int tid = threadIdx.x;
  const int lane = tid & 63, w = tid >> 6;
  const int tl = lane & 15, q = lane >> 4;
  const int b = blockIdx.x >> 10;
  const int n0 = (blockIdx.x & 1023) * 4;
  const __half* fTb = fT + ((size_t)(b << 12)) * 256;

  // stage window indices + zero garbage rows 40..47
  if (tid < 160) {
    int g = tid / 40, rem = tid % 40, m = rem / 10, kk = rem % 10;
    int meth = (m == 0) ? p0 : (m == 1) ? p1 : (m == 2) ? p2 : p3;
    idx[tid] = inds[((size_t)((b * 4 + meth) << 12) + n0 + g) * 10 + kk];
  }
  for (int i = tid; i < 2080; i += 512)
    ((int*)(smem + 40 * ROWB))[i] = 0;
  __syncthreads();

  float4v acc6[3][4];
#pragma unroll
  for (int mt = 0; mt < 3; ++mt)
#pragma unroll
    for (int t = 0; t < 4; ++t) acc6[mt][t] = (float4v){0.f, 0.f, 0.f, 0.f};

  const half8v* pk6 = (const half8v*)PK6;

#pragma unroll 1
  for (int hp = 0; hp < 2; ++hp) {
    // ---- P1: gather head-pair slab (128 fp16 cols), diff, layout d' = m*128+cl ----
#pragma unroll
    for (int s = 0; s < 2; ++s) {
      int slot = w * 2 + s;
      int g = slot >> 2, m = slot & 3;
      const __half2 cv = *(const __half2*)(fTb + (size_t)(n0 + g) * 256 + hp * 128 + 2 * lane);
      const int* ir = idx + (g * 4 + m) * 10;
#pragma unroll
      for (int kk = 0; kk < 10; ++kk) {
        __half2 v = *(const __half2*)(fTb + (size_t)ir[kk] * 256 + hp * 128 + 2 * lane);
        *(__half2*)(smem + (g * 10 + kk) * ROWB + m * 256 + lane * 4) = __hsub2(v, cv);
      }
    }
    __syncthreads();

    // ---- P2+P3: wave = (window g2, head hh); scores via MFMA + in-wave softmax ----
    {
      int g2 = w >> 1, hh = w & 1;
      float4v as = {0.f, 0.f, 0.f, 0.f};
      const char* rowbase = smem + (g2 * 10 + tl) * ROWB + hh * 128;
#pragma unroll
      for (int m4 = 0; m4 < 4; ++m4) {
        half8v a0 = *(const half8v*)(rowbase + m4 * 256 + q * 16);
        half8v a1 = *(const half8v*)(rowbase + m4 * 256 + 64 + q * 16);
        as = __builtin_amdgcn_mfma_f32_16x16x32_f16(a0, a0, as, 0, 0, 0);
        as = __builtin_amdgcn_mfma_f32_16x16x32_f16(a1, a1, as, 0, 0, 0);
      }
      bool vt = (tl < 10);
      float* scb = sc + (g2 * 2 + hh) * 100;
#pragma unroll
      for (int r = 0; r < 4; ++r) {
        float v = vt ? as[r] * 0.0625f : -1e30f;
        float m = v;
        m = fmaxf(m, __shfl_xor(m, 1));
        m = fmaxf(m, __shfl_xor(m, 2));
        m = fmaxf(m, __shfl_xor(m, 4));
        m = fmaxf(m, __shfl_xor(m, 8));
        float e = vt ? __expf(v - m) : 0.f;
        float su = e;
        su += __shfl_xor(su, 1);
        su += __shfl_xor(su, 2);
        su += __shfl_xor(su, 4);
        su += __shfl_xor(su, 8);
        float ar = e / su;
        int row = q * 4 + r;
        if (row < 10 && vt) scb[row * 10 + tl] = ar;
      }
    }
    __syncthreads();

    // ---- P4: out = attn @ x_diff, column-owned in place ----
    {
      int g4 = tid >> 7, cb2 = tid & 127;
#pragma unroll
      for (int hf = 0; hf < 2; ++hf) {
        int cc = cb2 + hf * 128;            // half2 index in [0,256)
        int hh = (cc & 63) >> 5;
        const float* arow = sc + (g4 * 2 + hh) * 100;
        __half2 xv[10];
#pragma unroll
        for (int j = 0; j < 10; ++j)
          xv[j] = *(const __half2*)(smem + (g4 * 10 + j) * ROWB + cc * 4);
#pragma unroll
        for (int kk = 0; kk < 10; ++kk) {
          float ax = 0.f, ay = 0.f;
#pragma unroll
          for (int j = 0; j < 10; ++j) {
            float wj = arow[kk * 10 + j];
            float2 f = __half22float2(xv[j]);
            ax = fmaf(wj, f.x, ax);
            ay = fmaf(wj, f.y, ay);
          }
          *(__half2*)(smem + (g4 * 10 + kk) * ROWB + cc * 4) = __floats2half2_rn(ax, ay);
        }
      }
    }
    __syncthreads();

    // ---- P6 partial: acc6 += out_slab @ Wd_slab^T ----
#pragma unroll 2
    for (int ks = 0; ks < 16; ++ks) {
      half8v a0 = *(const half8v*)(smem + (0  + tl) * ROWB + ks * 64 + q * 16);
      half8v a1 = *(const half8v*)(smem + (16 + tl) * ROWB + ks * 64 + q * 16);
      half8v a2 = *(const half8v*)(smem + (32 + tl) * ROWB + ks * 64 + q * 16);
#pragma unroll
      for (int t = 0; t < 4; ++t) {
        half8v bf = pk6[(size_t)(((w * 4 + t) * 32 + hp * 16 + ks)) * 64 + lane];
        acc6[0][t] = __builtin_amdgcn_mfma_f32_16x16x32_f16(a0, bf, acc6[0][t], 0, 0, 0);
        acc6[1][t] = __builtin_amdgcn_mfma_f32_16x16x32_f16(a1, bf, acc6[1][t], 0, 0, 0);
        acc6[2][t] = __builtin_amdgcn_mfma_f32_16x16x32_f16(a2, bf, acc6[2][t], 0, 0, 0);
      }
    }
    __syncthreads();
  }

  // ---- FU write (aliases slab; all P6 reads done) ----
#pragma unroll
  for (int mt = 0; mt < 3; ++mt)
#pragma unroll
    for (int t = 0; t < 4; ++t) {
      int o = (w * 4 + t) * 16 + tl;
#pragma unroll
      for (int r = 0; r < 4; ++r) {
        int row = 16 * mt + q * 4 + r;
        *(__half*)(smem + row * ROWB + o * 2) = __float2half(acc6[mt][t][r]);
      }
    }
  __syncthreads();

  // ---- P7: h = fused @ Wc^T + hc, then max_k + stats ----
  {
    constexpr int NT = O2 / 128;
    float4v acc7[3][NT];
#pragma unroll
    for (int mt = 0; mt < 3; ++mt)
#pragma unroll
      for (int t = 0; t < NT; ++t) acc7[mt][t] = (float4v){0.f, 0.f, 0.f, 0.f};
    const half8v* pk7 = (const half8v*)PK7;
#pragma unroll 2
    for (int ks = 0; ks < 16; ++ks) {
      half8v a0 = *(const half8v*)(smem + (0  + tl) * ROWB + ks * 64 + q * 16);
      half8v a1 = *(const half8v*)(smem + (16 + tl) * ROWB + ks * 64 + q * 16);
      half8v a2 = *(const half8v*)(smem + (32 + tl) * ROWB + ks * 64 + q * 16);
#pragma unroll
      for (int t = 0; t < NT; ++t) {
        half8v bf = pk7[(size_t)(((w * NT + t) * 16 + ks)) * 64 + lane];
        acc7[0][t] = __builtin_amdgcn_mfma_f32_16x16x32_f16(a0, bf, acc7[0][t], 0, 0, 0);
        acc7[1][t] = __builtin_amdgcn_mfma_f32_16x16x32_f16(a1, bf, acc7[1][t], 0, 0, 0);
        acc7[2][t] = __builtin_amdgcn_mfma_f32_16x16x32_f16(a2, bf, acc7[2][t], 0, 0, 0);
      }
    }
#pragma unroll
    for (int t = 0; t < NT; ++t) {
      int o2 = (w * NT + t) * 16 + tl;
      float hcv[4], mx[4], s1[4], s2[4];
#pragma unroll
      for (int g = 0; g < 4; ++g) {
        hcv[g] = __half2float(hc[((size_t)((b << 12) + n0 + g)) * O2 + o2]);
        mx[g] = -1e30f; s1[g] = 0.f; s2[g] = 0.f;
      }
#pragma unroll
      for (int mt = 0; mt < 3; ++mt)
#pragma unroll
        for (int r = 0; r < 4; ++r) {
          int gr = 16 * mt + 4 * q + r;
#pragma unroll
          for (int g = 0; g < 4; ++g) {
            if (gr >= 10 * g && gr < 10 * g + 10) {
              float v = acc7[mt][t][r] + hcv[g];
              mx[g] = fmaxf(mx[g], v);
              s1[g] += v;
              s2[g] = fmaf(v, v, s2[g]);
            }
          }
        }
#pragma unroll
      for (int g = 0; g < 4; ++g) {
        mx[g] = fmaxf(mx[g], __shfl_xor(mx[g], 16));
        mx[g] = fmaxf(mx[g], __shfl_xor(mx[g], 32));
      }
      float s1t = (s1[0] + s1[1]) + (s1[2] + s1[3]);
      float s2t = (s2[0] + s2[1]) + (s2[2] + s2[3]);
      s1t += __shfl_xor(s1t, 16); s1t += __shfl_xor(s1t, 32);
      s2t += __shfl_xor(s2t, 16); s2t += __shfl_xor(s2t, 32);
      if (q == 0) {
        // hmax layout [b][n][O2] -> 64B coalesced stores per g
#pragma unroll
        for (int g = 0; g < 4; ++g)
          hmax[((size_t)((b << 12) + n0 + g)) * O2 + o2] = mx[g];
        // atomic-free stats: one private slot per block
        S1[(size_t)blockIdx.x * O2 + o2] = s1t;
        S2[(size_t)blockIdx.x * O2 + o2] = s2t;
      }
    }
  }
}

// ---------------- stats reduce over 1024 block-slots per (b,o2) ----------------
__global__ __launch_bounds__(256) void gcn_stats2(const float* __restrict__ S1,
                                                  const float* __restrict__ S2,
                                                  float* __restrict__ mu,
                                                  float* __restrict__ rs,
                                                  int O2, float invNK) {
  __shared__ float r1[256], r2[256];
  int t = blockIdx.x;                 // t = b*O2 + o2, grid = 2*O2
  int b = t / O2, o2 = t - b * O2;
  const float* p1 = S1 + (size_t)b * 1024 * O2 + o2;
  const float* p2 = S2 + (size_t)b * 1024 * O2 + o2;
  float s1 = 0.f, s2 = 0.f;
  for (int i = threadIdx.x; i < 1024; i += 256) {
    s1 += p1[(size_t)i * O2];
    s2 += p2[(size_t)i * O2];
  }
  r1[threadIdx.x] = s1; r2[threadIdx.x] = s2;
  __syncthreads();
  for (int s = 128; s > 0; s >>= 1) {
    if (threadIdx.x < s) {
      r1[threadIdx.x] += r1[threadIdx.x + s];
      r2[threadIdx.x] += r2[threadIdx.x + s];
    }
    __syncthreads();
  }
  if (threadIdx.x == 0) {
    float m = r1[0] * invNK;
    float var = r2[0] * invNK - m * m;
    mu[t] = m;
    rs[t] = 1.0f / sqrtf(var + 1e-5f);
  }
}

// ---------------- old-style stats (final conv path, 64 atomic slots) ----------------
__global__ void gcn_stats(const float* __restrict__ S1, const float* __restrict__ S2,
                          float* __restrict__ mu, float* __restrict__ rs,
                          int O2, float invNK) {
  int t = threadIdx.x;
  if (t < 2 * O2) {
    float s1 = 0.f, s2 = 0.f;
    for (int s = 0; s < 64; ++s) {
      s1 += S1[(size_t)s * 2 * O2 + t];
      s2 += S2[(size_t)s * 2 * O2 + t];
    }
    float m = s1 * invNK;
    float var = s2 * invNK - m * m;
    mu[t] = m;
    rs[t] = 1.0f / sqrtf(var + 1e-5f);
  }
}

// ---------------- normalize + lrelu: hmax [b][n][O2] -> fp16 [b][n][O2] ----------------
__global__ void gcn_norm16(const float* __restrict__ src, const float* __restrict__ mu,
                           const float* __restrict__ rs, __half* __restrict__ out,
                           int omask, int bshift) {
  int idx = blockIdx.x * 256 + threadIdx.x;
  int o = idx & omask;
  int b = idx >> bshift;
  int t = b * (omask + 1) + o;
  float v = (src[idx] - mu[t]) * rs[t];
  v = v > 0.f ? v : 0.2f * v;
  out[idx] = __float2half(v);
}

// ---------------- final normalize + lrelu: [b][o][n] fp32 -> d_out ----------------
__global__ void gcn_norm(const float* __restrict__ src, const float* __restrict__ mu,
                         const float* __restrict__ rs, float* __restrict__ fN) {
  int idx = blockIdx.x * 256 + threadIdx.x;
  int bo = idx >> 12;
  float v = (src[idx] - mu[bo]) * rs[bo];
  v = v > 0.f ? v : 0.2f * v;
  fN[idx] = v;
}

// ---------------- final conv (fp32 VALU; f1/f2 fp16 [n][c]) ----------------
__global__ __launch_bounds__(256, 2) void gcn_final_conv(
    const float* __restrict__ feats, const __half* __restrict__ f1T,
    const __half* __restrict__ f2T, const float* __restrict__ Wc3,
    float* __restrict__ h3, float* __restrict__ S1, float* __restrict__ S2) {
  __shared__ float ftile[128 * 65];
  int x = blockIdx.x;
  int ob = x & 3, nb = (x >> 2) & 63, b = x >> 8;
  int lane = threadIdx.x & 63, wave = threadIdx.x >> 6;
  int n0 = nb * 64, o0 = ob * 64;
  float acc[16];
#pragma unroll
  for (int i = 0; i < 16; ++i) acc[i] = 0.f;
  for (int ct = 0; ct < 8; ++ct) {
    int cg0 = ct * 128;
    __syncthreads();
    if (cg0 < 256) {
      for (int idx = threadIdx.x; idx < 8192; idx += 256) {
        int ccc = idx >> 6, ln = idx & 63;
        ftile[ccc * 65 + ln] = feats[((size_t)(b * 256 + cg0 + ccc) << 12) + n0 + ln];
      }
    } else {
      for (int idx = threadIdx.x; idx < 8192; idx += 256) {
        int nl = idx >> 7, cl = idx & 127;
        int c = cg0 + cl;
        float v;
        if (c < 512) v = __half2float(f1T[((size_t)((b << 12) + n0 + nl)) * 256 + (c - 256)]);
        else         v = __half2float(f2T[((size_t)((b << 12) + n0 + nl)) * 512 + (c - 512)]);
        ftile[cl * 65 + nl] = v;
      }
    }
    __syncthreads();
    for (int c = 0; c < 128; ++c) {
      float fv = ftile[c * 65 + lane];
#pragma unroll
      for (int oi = 0; oi < 16; ++oi) {
        int o = o0 + wave * 16 + oi;
        acc[oi] = fmaf(Wc3[(size_t)o * 1024 + cg0 + c], fv, acc[oi]);
      }
    }
  }
  int slot = nb;
#pragma unroll
  for (int oi = 0; oi < 16; ++oi) {
    int o = o0 + wave * 16 + oi;
    float v = acc[oi];
    h3[((size_t)(b * 256 + o) << 12) + n0 + lane] = v;
    float s1 = v, s2 = v * v;
#pragma unroll
    for (int m = 1; m < 64; m <<= 1) {
      s1 += __shfl_xor(s1, m);
      s2 += __shfl_xor(s2, m);
    }
    if (lane == 0) {
      atomicAdd(&S1[(size_t)(slot * 2 + b) * 256 + o], s1);
      atomicAdd(&S2[(size_t)(slot * 2 + b) * 256 + o], s2);
    }
  }
}

// ---------------- launch ----------------
extern "C" void kernel_launch(void* const* d_in, const int* in_sizes, int n_in,
                              void* d_out, int out_size, void* d_ws, size_t ws_size,
                              hipStream_t stream) {
  (void)in_sizes; (void)n_in; (void)out_size; (void)ws_size;
  const float* coords  = (const float*)d_in[0];
  const float* feats   = (const float*)d_in[1];
  const float* W_lin1  = (const float*)d_in[2];
  const float* b_lin1  = (const float*)d_in[3];
  const float* W_lin2  = (const float*)d_in[4];
  const float* b_lin2  = (const float*)d_in[5];
  const float* W_conv1 = (const float*)d_in[6];
  const float* W_conv2 = (const float*)d_in[7];
  const float* W_conv3 = (const float*)d_in[8];
  char* ws = (char*)d_ws;

  float* F_MM    = (float*)(ws + OFF_MM);
  unsigned long long* KEYS = (unsigned long long*)(ws + OFF_KEYS);
  int* INDS      = (int*)(ws + OFF_INDS);
  _Float16* PK61 = (_Float16*)(ws + OFF_PK6_1);
  _Float16* PK62 = (_Float16*)(ws + OFF_PK6_2);
  _Float16* PK71 = (_Float16*)(ws + OFF_PK7_1);
  _Float16* PK72 = (_Float16*)(ws + OFF_PK7_2);
  float* WFOLD1  = (float*)(ws + OFF_WFOLD1);
  float* WFOLD2  = (float*)(ws + OFF_WFOLD2);
  float* WCOMB1  = (float*)(ws + OFF_WCOMB1);
  float* WCOMB2  = (float*)(ws + OFF_WCOMB2);
  _Float16* PC1  = (_Float16*)(ws + OFF_PC1);
  _Float16* PC2  = (_Float16*)(ws + OFF_PC2);
  float* BC1     = (float*)(ws + OFF_BC1);
  float* BC2     = (float*)(ws + OFF_BC2);
  __half* FEATST = (__half*)(ws + OFF_FEATST);
  __half* F1T    = (__half*)(ws + OFF_F1T);
  __half* F2T    = (__half*)(ws + OFF_F2T);
  float* HMAX1   = (float*)(ws + OFF_HMAX1);
  float* HMAX2   = (float*)(ws + OFF_HMAX2);
  __half* HC1    = (__half*)(ws + OFF_HC1);
  __half* HC2    = (__half*)(ws + OFF_HC2);
  float* S1W     = (float*)(ws + OFF_S1W);
  float* S2W     = (float*)(ws + OFF_S2W);
  float* H3      = (float*)(ws + OFF_H3);

  // only the final-conv atomic slots need zeroing
  (void)hipMemsetAsync(ws + OFF_S1f, 0, STATSF_B, stream);

  // weight prep
  gcn_foldF<<<512, 256, 0, stream>>>(W_lin1, WFOLD1);
  gcn_foldF<<<512, 256, 0, stream>>>(W_lin2, WFOLD2);
  gcn_wcomb<<<256, 256, 0, stream>>>(W_conv1, b_lin1, WFOLD1, WCOMB1, BC1);
  gcn_wcomb<<<512, 256, 0, stream>>>(W_conv2, b_lin2, WFOLD2, WCOMB2, BC2);
  gcn_packC<<<32, 256, 0, stream>>>(WCOMB1, PC1);
  gcn_packC<<<64, 256, 0, stream>>>(WCOMB2, PC2);
  gcn_pack6<<<256, 256, 0, stream>>>(W_lin1, PK61);
  gcn_pack6<<<256, 256, 0, stream>>>(W_lin2, PK62);
  gcn_pack7<<<64,  256, 0, stream>>>(W_conv1, PK71);
  gcn_pack7<<<128, 256, 0, stream>>>(W_conv2, PK72);

  // keys + sort + transpose
  gcn_minmax<<<6, 256, 0, stream>>>(coords, F_MM);
  gcn_keys<<<32, 256, 0, stream>>>(coords, F_MM, KEYS);
  gcn_sort<<<8, 1024, 0, stream>>>(KEYS, INDS);
  gcn_transpose<<<2048, 256, 0, stream>>>(feats, FEATST);

  // layer 1 (perm1 = [2,0,3,1])
  gcn_hc<256><<<512, 256, 0, stream>>>(FEATST, PC1, BC1, HC1);
  gcn_window<256><<<2048, 512, 0, stream>>>(
      FEATST, INDS, PK61, PK71, HC1,
      HMAX1, S1W, S2W, 2, 0, 3, 1);
  gcn_stats2<<<512, 256, 0, stream>>>(S1W, S2W,
                                      (float*)(ws + OFF_MU1), (float*)(ws + OFF_RS1),
                                      256, 1.0f / 40960.0f);
  gcn_norm16<<<8192, 256, 0, stream>>>(HMAX1, (float*)(ws + OFF_MU1), (float*)(ws + OFF_RS1),
                                       F1T, 255, 20);

  // layer 2 (perm2 = [1,3,0,2])
  gcn_hc<512><<<1024, 256, 0, stream>>>(F1T, PC2, BC2, HC2);
  gcn_window<512><<<2048, 512, 0, stream>>>(
      F1T, INDS, PK62, PK72, HC2,
      HMAX2, S1W, S2W, 1, 3, 0, 2);
  gcn_stats2<<<1024, 256, 0, stream>>>(S1W, S2W,
                                       (float*)(ws + OFF_MU2), (float*)(ws + OFF_RS2),
                                       512, 1.0f / 40960.0f);
  gcn_norm16<<<16384, 256, 0, stream>>>(HMAX2, (float*)(ws + OFF_MU2), (float*)(ws + OFF_RS2),
                                        F2T, 511, 21);

  // final conv + norm
  gcn_final_conv<<<512, 256, 0, stream>>>(feats, F1T, F2T, W_conv3,
                                          H3, (float*)(ws + OFF_S1f), (float*)(ws + OFF_S2f));
  gcn_stats<<<1, 1024, 0, stream>>>((float*)(ws + OFF_S1f), (float*)(ws + OFF_S2f),
                                    (float*)(ws + OFF_MU3), (float*)(ws + OFF_RS3),
                                    256, 1.0f / 4096.0f);
  gcn_norm<<<8192, 256, 0, stream>>>(H3, (float*)(ws + OFF_MU3), (float*)(ws + OFF_RS3),
                                     (float*)d_out);
}

// Round 6
// 857.216 us; speedup vs baseline: 1.5831x; 1.3051x over previous
//
#include <hip/hip_runtime.h>
#include <hip/hip_fp16.h>

// =====================================================================
// GCN pipeline on MI355X, round 6:
//  - final conv -> MFMA (was fp32 VALU, 342us, MfmaUtil=0)
//  - A-sources already fp16 [n][c]; Wc3 packed fragment-major
//  - atomic-free slot stats everywhere; no memset needed
//  - transpose-norm epilogue (coalesced both sides)
// =====================================================================

typedef _Float16 half8v  __attribute__((ext_vector_type(8)));
typedef float    float4v __attribute__((ext_vector_type(4)));

// ---------------- workspace layout (bytes) ----------------
constexpr size_t OFF_S1f    = 0;                            // (legacy, unused)
constexpr size_t OFF_S2f    = OFF_S1f + 64ull*2*256*4;
constexpr size_t STATSF_B   = OFF_S2f + 64ull*2*256*4;
constexpr size_t OFF_MU1    = STATSF_B;
constexpr size_t OFF_RS1    = OFF_MU1 + 2048;
constexpr size_t OFF_MU2    = OFF_RS1 + 2048;
constexpr size_t OFF_RS2    = OFF_MU2 + 4096;
constexpr size_t OFF_MU3    = OFF_RS2 + 4096;
constexpr size_t OFF_RS3    = OFF_MU3 + 2048;
constexpr size_t OFF_MM     = OFF_RS3 + 2048;               // 12 floats
constexpr size_t OFF_KEYS   = OFF_MM + 256;
constexpr size_t OFF_INDS   = OFF_KEYS + 8ull*4096*8;
constexpr size_t OFF_PK6_1  = OFF_INDS + 8ull*4096*10*4;    // 1 MB
constexpr size_t OFF_PK6_2  = OFF_PK6_1 + 512ull*1024*2;
constexpr size_t OFF_PK7_1  = OFF_PK6_2 + 512ull*1024*2;
constexpr size_t OFF_PK7_2  = OFF_PK7_1 + 256ull*512*2;
constexpr size_t OFF_WFOLD1 = OFF_PK7_2 + 512ull*512*2;
constexpr size_t OFF_WFOLD2 = OFF_WFOLD1 + 512ull*256*4;
constexpr size_t OFF_WCOMB1 = OFF_WFOLD2 + 512ull*256*4;
constexpr size_t OFF_WCOMB2 = OFF_WCOMB1 + 256ull*256*4;
constexpr size_t OFF_PC1    = OFF_WCOMB2 + 512ull*256*4;
constexpr size_t OFF_PC2    = OFF_PC1 + 256ull*256*2;
constexpr size_t OFF_BC1    = OFF_PC2 + 512ull*256*2;
constexpr size_t OFF_BC2    = OFF_BC1 + 1024;
constexpr size_t OFF_FEATST = OFF_BC2 + 2048;               // (B,N,256) fp16
constexpr size_t OFF_F1T    = OFF_FEATST + 2ull*4096*256*2; // (B,N,256) fp16
constexpr size_t OFF_F2T    = OFF_F1T   + 2ull*4096*256*2;  // (B,N,512) fp16
constexpr size_t OFF_HMAX1  = OFF_F2T   + 2ull*4096*512*2;  // (B,N,256) fp32
constexpr size_t OFF_HMAX2  = OFF_HMAX1 + 2ull*4096*256*4;  // (B,N,512) fp32
constexpr size_t OFF_HC1    = OFF_HMAX2 + 2ull*4096*512*4;  // fp16 (B*N,256)
constexpr size_t OFF_HC2    = OFF_HC1   + 8192ull*256*2;    // fp16 (B*N,512)
constexpr size_t OFF_S1W    = OFF_HC2   + 8192ull*512*2;    // [2048][<=512] f
constexpr size_t OFF_S2W    = OFF_S1W   + 2048ull*512*4;
constexpr size_t OFF_PF3    = OFF_S2W   + 2048ull*512*4;    // 512 KB packed Wc3
constexpr size_t WS_NEED    = OFF_PF3   + 256ull*1024*2;
// lifetime-disjoint alias: H3 [b][n][256] fp32 (hmax1 dead after norm16-L1)
constexpr size_t OFF_H3     = OFF_HMAX1;

// ---------------- helpers ----------------
__device__ __forceinline__ int gcn_quant1(float c, float cmin, float scale) {
  float q = floorf(__fmul_rn(__fsub_rn(c, cmin), scale));
  q = fminf(fmaxf(q, 0.0f), 1023.0f);
  return (int)q;
}

__device__ __forceinline__ unsigned int gcn_morton3(int x, int y, int z) {
  unsigned int key = 0u;
#pragma unroll
  for (int b = 0; b < 10; ++b) {
    key |= ((unsigned)((x >> b) & 1)) << (3 * b + 2);
    key |= ((unsigned)((y >> b) & 1)) << (3 * b + 1);
    key |= ((unsigned)((z >> b) & 1)) << (3 * b + 0);
  }
  return key;
}

__device__ __forceinline__ unsigned int gcn_hilbert3(int x, int y, int z) {
  int X0 = x, X1 = y, X2 = z;
  for (int Q = 512; Q > 1; Q >>= 1) {
    int P = Q - 1;
    if (X0 & Q) X0 ^= P;
    {
      int t = (X0 ^ X1) & P;
      if (X1 & Q) { X0 ^= P; } else { X0 ^= t; X1 ^= t; }
    }
    {
      int t = (X0 ^ X2) & P;
      if (X2 & Q) { X0 ^= P; } else { X0 ^= t; X2 ^= t; }
    }
  }
  X1 ^= X0;
  X2 ^= X1;
  int t = 0;
  for (int Q = 512; Q > 1; Q >>= 1)
    if (X2 & Q) t ^= (Q - 1);
  X0 ^= t; X1 ^= t; X2 ^= t;
  unsigned int key = 0u;
#pragma unroll
  for (int b = 9; b >= 0; --b) {
    key = (key << 1) | (unsigned)((X0 >> b) & 1);
    key = (key << 1) | (unsigned)((X1 >> b) & 1);
    key = (key << 1) | (unsigned)((X2 >> b) & 1);
  }
  return key;
}

// ---------------- weight prep ----------------
__global__ void gcn_foldF(const float* __restrict__ W, float* __restrict__ Wf) {
  int i = blockIdx.x * 256 + threadIdx.x;   // 512*256
  int o = i >> 8, c = i & 255;
  float4 w = ((const float4*)W)[(size_t)o * 512 + c];
  Wf[i] = w.x + w.y + w.z + w.w;
}

__global__ void gcn_wcomb(const float* __restrict__ Wc, const float* __restrict__ blin,
                          const float* __restrict__ WfoldF, float* __restrict__ Wcomb,
                          float* __restrict__ bc) {
  __shared__ float wrow[512];
  int o2 = blockIdx.x, tid = threadIdx.x;
  wrow[tid] = Wc[(size_t)o2 * 512 + tid];
  wrow[tid + 256] = Wc[(size_t)o2 * 512 + tid + 256];
  __syncthreads();
  float acc = 0.f;
  for (int o = 0; o < 512; ++o)
    acc = fmaf(wrow[o], WfoldF[(size_t)o * 256 + tid], acc);
  Wcomb[(size_t)o2 * 256 + tid] = acc;
  if (tid == 0) {
    float s = 0.f;
    for (int o = 0; o < 512; ++o) s += wrow[o] * blin[o];
    bc[o2] = s;
  }
}

__global__ void gcn_packC(const float* __restrict__ Wcomb, _Float16* __restrict__ P) {
  int i = blockIdx.x * 256 + threadIdx.x;   // (O2/16)*8*64
  int lane = i & 63, ks = (i >> 6) & 7, nt = i >> 9;
  int tl = lane & 15, q = lane >> 4;
  int n = nt * 16 + tl;
  _Float16 tmp[8];
#pragma unroll
  for (int j = 0; j < 8; ++j)
    tmp[j] = (_Float16)Wcomb[(size_t)n * 256 + ks * 32 + q * 8 + j];
  *(half8v*)(P + (size_t)i * 8) = *(half8v*)tmp;
}

// P6 pack: k = hp*512 + m*128 + cl  ->  orig col 1024 + 4*(128*hp+cl) + m
__global__ void gcn_pack6(const float* __restrict__ W, _Float16* __restrict__ P) {
  int i = blockIdx.x * 256 + threadIdx.x;   // 65536
  int lane = i & 63, ks = (i >> 6) & 31, nt = i >> 11;
  int tl = lane & 15, q = lane >> 4;
  int o = nt * 16 + tl;
  _Float16 tmp[8];
#pragma unroll
  for (int j = 0; j < 8; ++j) {
    int k = ks * 32 + q * 8 + j;
    int hp = k >> 9, r = k & 511, m = r >> 7, cl = r & 127;
    int col = 1024 + 4 * (128 * hp + cl) + m;
    tmp[j] = (_Float16)W[(size_t)o * 2048 + col];
  }
  *(half8v*)(P + (size_t)i * 8) = *(half8v*)tmp;
}

__global__ void gcn_pack7(const float* __restrict__ W, _Float16* __restrict__ P) {
  int i = blockIdx.x * 256 + threadIdx.x;   // O2*64
  int lane = i & 63, ks = (i >> 6) & 15, nt = i >> 10;
  int tl = lane & 15, q = lane >> 4;
  int o2 = nt * 16 + tl;
  int c2 = ks * 32 + q * 8;
  _Float16 tmp[8];
#pragma unroll
  for (int j = 0; j < 8; ++j)
    tmp[j] = (_Float16)W[(size_t)o2 * 512 + c2 + j];
  *(half8v*)(P + (size_t)i * 8) = *(half8v*)tmp;
}

// final conv weight pack: Wc3 (256 x 1024), frag f = (nt*32+ksg)*64+lane
__global__ void gcn_packF(const float* __restrict__ W, _Float16* __restrict__ P) {
  int i = blockIdx.x * 256 + threadIdx.x;   // 32768
  int lane = i & 63, ksg = (i >> 6) & 31, nt = i >> 11;
  int tl = lane & 15, q = lane >> 4;
  int o = nt * 16 + tl;
  _Float16 tmp[8];
#pragma unroll
  for (int j = 0; j < 8; ++j)
    tmp[j] = (_Float16)W[(size_t)o * 1024 + ksg * 32 + q * 8 + j];
  *(half8v*)(P + (size_t)i * 8) = *(half8v*)tmp;
}

// ---------------- hc precompute (fp16 in / fp16 out) ----------------
template <int O2>
__global__ __launch_bounds__(256) void gcn_hc(const __half* __restrict__ src,
                                              const _Float16* __restrict__ PC,
                                              const float* __restrict__ bc,
                                              __half* __restrict__ out) {
  constexpr int NB = O2 / 64;
  __shared__ __align__(16) _Float16 As[64 * 264];
  int nb = blockIdx.x % NB, mb = blockIdx.x / NB;
  int tid = threadIdx.x;
  const __half2* s2 = (const __half2*)(src + (size_t)mb * 64 * 256);
  for (int idx = tid; idx < 64 * 128; idx += 256) {
    int row = idx >> 7, cp = idx & 127;
    __half2 v = s2[row * 128 + cp];
    *(__half2*)((char*)As + row * 528 + cp * 4) = v;
  }
  __syncthreads();
  int lane = tid & 63, w = tid >> 6, tl = lane & 15, q = lane >> 4;
  float4v acc[4];
#pragma unroll
  for (int t = 0; t < 4; ++t) acc[t] = (float4v){0.f, 0.f, 0.f, 0.f};
  const half8v* pc = (const half8v*)PC;
#pragma unroll
  for (int ks = 0; ks < 8; ++ks) {
    half8v a = *(const half8v*)((const char*)As + (w * 16 + tl) * 528 + ks * 64 + q * 16);
#pragma unroll
    for (int t = 0; t < 4; ++t) {
      half8v bf = pc[(size_t)(((nb * 4 + t) * 8 + ks)) * 64 + lane];
      acc[t] = __builtin_amdgcn_mfma_f32_16x16x32_f16(a, bf, acc[t], 0, 0, 0);
    }
  }
#pragma unroll
  for (int t = 0; t < 4; ++t) {
    int o = (nb * 4 + t) * 16 + tl;
    float bb = bc[o];
#pragma unroll
    for (int r = 0; r < 4; ++r) {
      int row = mb * 64 + w * 16 + q * 4 + r;
      out[(size_t)row * O2 + o] = __float2half(acc[t][r] + bb);
    }
  }
}

// ---------------- quantize prep ----------------
__global__ void gcn_minmax(const float* __restrict__ coords, float* __restrict__ mm) {
  __shared__ float slo[256], shi[256];
  int d = blockIdx.x, tid = threadIdx.x;
  float lo = 1e30f, hi = -1e30f;
  for (int i = tid; i < 4096; i += 256) {
    float v = coords[(size_t)d * 4096 + i];
    lo = fminf(lo, v);
    hi = fmaxf(hi, v);
  }
  slo[tid] = lo; shi[tid] = hi;
  __syncthreads();
  for (int s = 128; s > 0; s >>= 1) {
    if (tid < s) {
      slo[tid] = fminf(slo[tid], slo[tid + s]);
      shi[tid] = fmaxf(shi[tid], shi[tid + s]);
    }
    __syncthreads();
  }
  if (tid == 0) {
    mm[d] = slo[0];
    mm[6 + d] = 1023.0f / ((shi[0] - slo[0]) + 1e-6f);
  }
}

__global__ void gcn_keys(const float* __restrict__ coords, const float* __restrict__ mm,
                         unsigned long long* __restrict__ keys) {
  int idx = blockIdx.x * 256 + threadIdx.x;
  int b = idx >> 12, n = idx & 4095;
  const float* cb = coords + (size_t)b * 3 * 4096;
  int q0 = gcn_quant1(cb[n],        mm[b * 3 + 0], mm[6 + b * 3 + 0]);
  int q1 = gcn_quant1(cb[4096 + n], mm[b * 3 + 1], mm[6 + b * 3 + 1]);
  int q2 = gcn_quant1(cb[8192 + n], mm[b * 3 + 2], mm[6 + b * 3 + 2]);
  unsigned long long nn = (unsigned long long)(unsigned)n;
  size_t base = ((size_t)b * 4) * 4096 + n;
  keys[base]         = ((unsigned long long)gcn_morton3(q0, q1, q2) << 12) | nn;
  keys[base + 4096]  = ((unsigned long long)gcn_morton3(q1, q0, q2) << 12) | nn;
  keys[base + 8192]  = ((unsigned long long)gcn_hilbert3(q0, q1, q2) << 12) | nn;
  keys[base + 12288] = ((unsigned long long)gcn_hilbert3(q1, q0, q2) << 12) | nn;
}

// ---------------- bitonic sort (stable argsort replica) + windows ----------------
__global__ __launch_bounds__(1024) void gcn_sort(const unsigned long long* __restrict__ keys,
                                                 int* __restrict__ inds) {
  __shared__ unsigned long long a[4096];
  int g = blockIdx.x, tid = threadIdx.x;
  for (int i = tid; i < 4096; i += 1024) a[i] = keys[(size_t)g * 4096 + i];
  __syncthreads();
  for (int k = 2; k <= 4096; k <<= 1) {
    for (int j = k >> 1; j > 0; j >>= 1) {
      for (int t = tid; t < 2048; t += 1024) {
        int i = 2 * t - (t & (j - 1));
        int p = i + j;
        bool up = (i & k) == 0;
        unsigned long long x = a[i], y = a[p];
        if ((x > y) == up) { a[i] = y; a[p] = x; }
      }
      __syncthreads();
    }
  }
  for (int i = tid; i < 4096; i += 1024) {
    int start = i - 5; if (start < 0) start = 0;
    int endm1 = i + 5; if (endm1 > 4095) endm1 = 4095;
#pragma unroll
    for (int kk = 0; kk < 10; ++kk) {
      int pos = start + kk; if (pos > endm1) pos = endm1;
      inds[((size_t)g * 4096 + i) * 10 + kk] = (int)(a[pos] & 0xFFFULL);
    }
  }
}

// ---------------- transpose (B,C,N) fp32 -> (B,N,C) fp16 ----------------
__global__ void gcn_transpose(const float* __restrict__ feats, __half* __restrict__ fT) {
  __shared__ float t[32][33];
  int blk = blockIdx.x;
  int cb = blk & 7, nb = (blk >> 3) & 127, b = blk >> 10;
  int tx = threadIdx.x & 31, ty = threadIdx.x >> 5;
#pragma unroll
  for (int i = 0; i < 4; ++i) {
    int c = cb * 32 + ty + i * 8;
    t[ty + i * 8][tx] = feats[((size_t)(b * 256 + c) << 12) + nb * 32 + tx];
  }
  __syncthreads();
  if (tx < 16) {
#pragma unroll
    for (int i = 0; i < 4; ++i) {
      int nl = ty + i * 8;
      int n = nb * 32 + nl;
      __half2 hv = __floats2half2_rn(t[2 * tx][nl], t[2 * tx + 1][nl]);
      *(__half2*)(fT + ((size_t)((b << 12) + n)) * 256 + cb * 32 + 2 * tx) = hv;
    }
  }
}

// ---------------- fused 4-window MFMA kernel ----------------
// slab/FU: 48 rows x 1040 B at 0 (aliased in time); SC 800 f at 49920; IDX at 53120
constexpr int ROWB   = 1040;
constexpr int SM_SC  = 49920;
constexpr int SM_IDX = 53120;
constexpr int SM_TOT = 53760;

template <int O2>
__global__ __launch_bounds__(512, 4) void gcn_window(
    const __half* __restrict__ fT, const int* __restrict__ inds,
    const _Float16* __restrict__ PK6, const _Float16* __restrict__ PK7,
    const __half* __restrict__ hc,
    float* __restrict__ hmax, float* __restrict__ S1, float* __restrict__ S2,
    int p0, int p1, int p2, int p3) {
  __shared__ __align__(16) char smem[SM_TOT];
  float* sc  = (float*)(smem + SM_SC);
  int*   idx = (int*)(smem + SM_IDX);

  const int tid = threadIdx.x;
  const int lane = tid & 63, w = tid >> 6;
  const int tl = lane & 15, q = lane >> 4;
  const int b = blockIdx.x >> 10;
  const int n0 = (blockIdx.x & 1023) * 4;
  const __half* fTb = fT + ((size_t)(b << 12)) * 256;

  // stage window indices + zero garbage rows 40..47
  if (tid < 160) {
    int g = tid / 40, rem = tid % 40, m = rem / 10, kk = rem % 10;
    int meth = (m == 0) ? p0 : (m == 1) ? p1 : (m == 2) ? p2 : p3;
    idx[tid] = inds[((size_t)((b * 4 + meth) << 12) + n0 + g) * 10 + kk];
  }
  for (int i = tid; i < 2080; i += 512)
    ((int*)(smem + 40 * ROWB))[i] = 0;
  __syncthreads();

  float4v acc6[3][4];
#pragma unroll
  for (int mt = 0; mt < 3; ++mt)
#pragma unroll
    for (int t = 0; t < 4; ++t) acc6[mt][t] = (float4v){0.f, 0.f, 0.f, 0.f};

  const half8v* pk6 = (const half8v*)PK6;

#pragma unroll 1
  for (int hp = 0; hp < 2; ++hp) {
    // ---- P1: gather head-pair slab (128 fp16 cols), diff, layout d' = m*128+cl ----
#pragma unroll
    for (int s = 0; s < 2; ++s) {
      int slot = w * 2 + s;
      int g = slot >> 2, m = slot & 3;
      const __half2 cv = *(const __half2*)(fTb + (size_t)(n0 + g) * 256 + hp * 128 + 2 * lane);
      const int* ir = idx + (g * 4 + m) * 10;
#pragma unroll
      for (int kk = 0; kk < 10; ++kk) {
        __half2 v = *(const __half2*)(fTb + (size_t)ir[kk] * 256 + hp * 128 + 2 * lane);
        *(__half2*)(smem + (g * 10 + kk) * ROWB + m * 256 + lane * 4) = __hsub2(v, cv);
      }
    }
    __syncthreads();

    // ---- P2+P3: wave = (window g2, head hh); scores via MFMA + in-wave softmax ----
    {
      int g2 = w >> 1, hh = w & 1;
      float4v as = {0.f, 0.f, 0.f, 0.f};
      const char* rowbase = smem + (g2 * 10 + tl) * ROWB + hh * 128;
#pragma unroll
      for (int m4 = 0; m4 < 4; ++m4) {
        half8v a0 = *(const half8v*)(rowbase + m4 * 256 + q * 16);
        half8v a1 = *(const half8v*)(rowbase + m4 * 256 + 64 + q * 16);
        as = __builtin_amdgcn_mfma_f32_16x16x32_f16(a0, a0, as, 0, 0, 0);
        as = __builtin_amdgcn_mfma_f32_16x16x32_f16(a1, a1, as, 0, 0, 0);
      }
      bool vt = (tl < 10);
      float* scb = sc + (g2 * 2 + hh) * 100;
#pragma unroll
      for (int r = 0; r < 4; ++r) {
        float v = vt ? as[r] * 0.0625f : -1e30f;
        float m = v;
        m = fmaxf(m, __shfl_xor(m, 1));
        m = fmaxf(m, __shfl_xor(m, 2));
        m = fmaxf(m, __shfl_xor(m, 4));
        m = fmaxf(m, __shfl_xor(m, 8));
        float e = vt ? __expf(v - m) : 0.f;
        float su = e;
        su += __shfl_xor(su, 1);
        su += __shfl_xor(su, 2);
        su += __shfl_xor(su, 4);
        su += __shfl_xor(su, 8);
        float ar = e / su;
        int row = q * 4 + r;
        if (row < 10 && vt) scb[row * 10 + tl] = ar;
      }
    }
    __syncthreads();

    // ---- P4: out = attn @ x_diff, column-owned in place ----
    {
      int g4 = tid >> 7, cb2 = tid & 127;
#pragma unroll
      for (int hf = 0; hf < 2; ++hf) {
        int cc = cb2 + hf * 128;            // half2 index in [0,256)
        int hh = (cc & 63) >> 5;
        const float* arow = sc + (g4 * 2 + hh) * 100;
        __half2 xv[10];
#pragma unroll
        for (int j = 0; j < 10; ++j)
          xv[j] = *(const __half2*)(smem + (g4 * 10 + j) * ROWB + cc * 4);
#pragma unroll
        for (int kk = 0; kk < 10; ++kk) {
          float ax = 0.f, ay = 0.f;
#pragma unroll
          for (int j = 0; j < 10; ++j) {
            float wj = arow[kk * 10 + j];
            float2 f = __half22float2(xv[j]);
            ax = fmaf(wj, f.x, ax);
            ay = fmaf(wj, f.y, ay);
          }
          *(__half2*)(smem + (g4 * 10 + kk) * ROWB + cc * 4) = __floats2half2_rn(ax, ay);
        }
      }
    }
    __syncthreads();

    // ---- P6 partial: acc6 += out_slab @ Wd_slab^T ----
#pragma unroll 2
    for (int ks = 0; ks < 16; ++ks) {
      half8v a0 = *(const half8v*)(smem + (0  + tl) * ROWB + ks * 64 + q * 16);
      half8v a1 = *(const half8v*)(smem + (16 + tl) * ROWB + ks * 64 + q * 16);
      half8v a2 = *(const half8v*)(smem + (32 + tl) * ROWB + ks * 64 + q * 16);
#pragma unroll
      for (int t = 0; t < 4; ++t) {
        half8v bf = pk6[(size_t)(((w * 4 + t) * 32 + hp * 16 + ks)) * 64 + lane];
        acc6[0][t] = __builtin_amdgcn_mfma_f32_16x16x32_f16(a0, bf, acc6[0][t], 0, 0, 0);
        acc6[1][t] = __builtin_amdgcn_mfma_f32_16x16x32_f16(a1, bf, acc6[1][t], 0, 0, 0);
        acc6[2][t] = __builtin_amdgcn_mfma_f32_16x16x32_f16(a2, bf, acc6[2][t], 0, 0, 0);
      }
    }
    __syncthreads();
  }

  // ---- FU write (aliases slab; all P6 reads done) ----
#pragma unroll
  for (int mt = 0; mt < 3; ++mt)
#pragma unroll
    for (int t = 0; t < 4; ++t) {
      int o = (w * 4 + t) * 16 + tl;
#pragma unroll
      for (int r = 0; r < 4; ++r) {
        int row = 16 * mt + q * 4 + r;
        *(__half*)(smem + row * ROWB + o * 2) = __float2half(acc6[mt][t][r]);
      }
    }
  __syncthreads();

  // ---- P7: h = fused @ Wc^T + hc, then max_k + stats ----
  {
    constexpr int NT = O2 / 128;
    float4v acc7[3][NT];
#pragma unroll
    for (int mt = 0; mt < 3; ++mt)
#pragma unroll
      for (int t = 0; t < NT; ++t) acc7[mt][t] = (float4v){0.f, 0.f, 0.f, 0.f};
    const half8v* pk7 = (const half8v*)PK7;
#pragma unroll 2
    for (int ks = 0; ks < 16; ++ks) {
      half8v a0 = *(const half8v*)(smem + (0  + tl) * ROWB + ks * 64 + q * 16);
      half8v a1 = *(const half8v*)(smem + (16 + tl) * ROWB + ks * 64 + q * 16);
      half8v a2 = *(const half8v*)(smem + (32 + tl) * ROWB + ks * 64 + q * 16);
#pragma unroll
      for (int t = 0; t < NT; ++t) {
        half8v bf = pk7[(size_t)(((w * NT + t) * 16 + ks)) * 64 + lane];
        acc7[0][t] = __builtin_amdgcn_mfma_f32_16x16x32_f16(a0, bf, acc7[0][t], 0, 0, 0);
        acc7[1][t] = __builtin_amdgcn_mfma_f32_16x16x32_f16(a1, bf, acc7[1][t], 0, 0, 0);
        acc7[2][t] = __builtin_amdgcn_mfma_f32_16x16x32_f16(a2, bf, acc7[2][t], 0, 0, 0);
      }
    }
#pragma unroll
    for (int t = 0; t < NT; ++t) {
      int o2 = (w * NT + t) * 16 + tl;
      float hcv[4], mx[4], s1[4], s2[4];
#pragma unroll
      for (int g = 0; g < 4; ++g) {
        hcv[g] = __half2float(hc[((size_t)((b << 12) + n0 + g)) * O2 + o2]);
        mx[g] = -1e30f; s1[g] = 0.f; s2[g] = 0.f;
      }
#pragma unroll
      for (int mt = 0; mt < 3; ++mt)
#pragma unroll
        for (int r = 0; r < 4; ++r) {
          int gr = 16 * mt + 4 * q + r;
#pragma unroll
          for (int g = 0; g < 4; ++g) {
            if (gr >= 10 * g && gr < 10 * g + 10) {
              float v = acc7[mt][t][r] + hcv[g];
              mx[g] = fmaxf(mx[g], v);
              s1[g] += v;
              s2[g] = fmaf(v, v, s2[g]);
            }
          }
        }
#pragma unroll
      for (int g = 0; g < 4; ++g) {
        mx[g] = fmaxf(mx[g], __shfl_xor(mx[g], 16));
        mx[g] = fmaxf(mx[g], __shfl_xor(mx[g], 32));
      }
      float s1t = (s1[0] + s1[1]) + (s1[2] + s1[3]);
      float s2t = (s2[0] + s2[1]) + (s2[2] + s2[3]);
      s1t += __shfl_xor(s1t, 16); s1t += __shfl_xor(s1t, 32);
      s2t += __shfl_xor(s2t, 16); s2t += __shfl_xor(s2t, 32);
      if (q == 0) {
        // hmax layout [b][n][O2] -> coalesced stores per g
#pragma unroll
        for (int g = 0; g < 4; ++g)
          hmax[((size_t)((b << 12) + n0 + g)) * O2 + o2] = mx[g];
        S1[(size_t)blockIdx.x * O2 + o2] = s1t;
        S2[(size_t)blockIdx.x * O2 + o2] = s2t;
      }
    }
  }
}

// ---------------- final conv via MFMA ----------------
// block: 64 rows x 64 outputs, K=1024 staged in 4 chunks of 256
__global__ __launch_bounds__(256) void gcn_final_mfma(
    const __half* __restrict__ featsT, const __half* __restrict__ f1T,
    const __half* __restrict__ f2T, const _Float16* __restrict__ PF,
    float* __restrict__ h3, float* __restrict__ S1, float* __restrict__ S2) {
  __shared__ __align__(16) char As[64 * 528];
  const int nb = blockIdx.x & 3, mb = blockIdx.x >> 2;   // mb 0..127
  const int tid = threadIdx.x;
  const int lane = tid & 63, w = tid >> 6, tl = lane & 15, q = lane >> 4;
  const int b = mb >> 6;
  const int nbase = (mb & 63) * 64;
  float4v acc[4];
#pragma unroll
  for (int t = 0; t < 4; ++t) acc[t] = (float4v){0.f, 0.f, 0.f, 0.f};
  const half8v* pf = (const half8v*)PF;
#pragma unroll 1
  for (int kc = 0; kc < 4; ++kc) {
    __syncthreads();
    for (int idx = tid; idx < 64 * 128; idx += 256) {
      int nl = idx >> 7, cp = idx & 127;
      size_t rowg = (size_t)(b << 12) + nbase + nl;
      __half2 v;
      if (kc == 0)      v = *(const __half2*)(featsT + rowg * 256 + cp * 2);
      else if (kc == 1) v = *(const __half2*)(f1T + rowg * 256 + cp * 2);
      else if (kc == 2) v = *(const __half2*)(f2T + rowg * 512 + cp * 2);
      else              v = *(const __half2*)(f2T + rowg * 512 + 256 + cp * 2);
      *(__half2*)(As + nl * 528 + cp * 4) = v;
    }
    __syncthreads();
#pragma unroll
    for (int ks = 0; ks < 8; ++ks) {
      int ksg = kc * 8 + ks;
      half8v a = *(const half8v*)(As + (w * 16 + tl) * 528 + ks * 64 + q * 16);
#pragma unroll
      for (int t = 0; t < 4; ++t) {
        half8v bf = pf[(size_t)(((nb * 4 + t) * 32 + ksg)) * 64 + lane];
        acc[t] = __builtin_amdgcn_mfma_f32_16x16x32_f16(a, bf, acc[t], 0, 0, 0);
      }
    }
  }
#pragma unroll
  for (int t = 0; t < 4; ++t) {
    int o = (nb * 4 + t) * 16 + tl;
    float s1 = 0.f, s2 = 0.f;
#pragma unroll
    for (int r = 0; r < 4; ++r) {
      float v = acc[t][r];
      int n = nbase + w * 16 + q * 4 + r;
      h3[((size_t)(b << 12) + n) * 256 + o] = v;
      s1 += v;
      s2 = fmaf(v, v, s2);
    }
    s1 += __shfl_xor(s1, 16); s1 += __shfl_xor(s1, 32);
    s2 += __shfl_xor(s2, 16); s2 += __shfl_xor(s2, 32);
    if (q == 0) {
      int slot = mb * 4 + w;           // 0..511; b = slot>>8
      S1[(size_t)slot * 256 + o] = s1;
      S2[(size_t)slot * 256 + o] = s2;
    }
  }
}

// ---------------- stats reduce over nslots block-slots per (b,o2) ----------------
__global__ __launch_bounds__(256) void gcn_stats2(const float* __restrict__ S1,
                                                  const float* __restrict__ S2,
                                                  float* __restrict__ mu,
                                                  float* __restrict__ rs,
                                                  int O2, int nslots, float invNK) {
  __shared__ float r1[256], r2[256];
  int t = blockIdx.x;                 // t = b*O2 + o2, grid = 2*O2
  int b = t / O2, o2 = t - b * O2;
  const float* p1 = S1 + (size_t)b * nslots * O2 + o2;
  const float* p2 = S2 + (size_t)b * nslots * O2 + o2;
  float s1 = 0.f, s2 = 0.f;
  for (int i = threadIdx.x; i < nslots; i += 256) {
    s1 += p1[(size_t)i * O2];
    s2 += p2[(size_t)i * O2];
  }
  r1[threadIdx.x] = s1; r2[threadIdx.x] = s2;
  __syncthreads();
  for (int s = 128; s > 0; s >>= 1) {
    if (threadIdx.x < s) {
      r1[threadIdx.x] += r1[threadIdx.x + s];
      r2[threadIdx.x] += r2[threadIdx.x + s];
    }
    __syncthreads();
  }
  if (threadIdx.x == 0) {
    float m = r1[0] * invNK;
    float var = r2[0] * invNK - m * m;
    mu[t] = m;
    rs[t] = 1.0f / sqrtf(var + 1e-5f);
  }
}

// ---------------- normalize + lrelu: hmax [b][n][O2] -> fp16 [b][n][O2] ----------------
__global__ void gcn_norm16(const float* __restrict__ src, const float* __restrict__ mu,
                           const float* __restrict__ rs, __half* __restrict__ out,
                           int omask, int bshift) {
  int idx = blockIdx.x * 256 + threadIdx.x;
  int o = idx & omask;
  int b = idx >> bshift;
  int t = b * (omask + 1) + o;
  float v = (src[idx] - mu[t]) * rs[t];
  v = v > 0.f ? v : 0.2f * v;
  out[idx] = __float2half(v);
}

// ---------------- final: transpose-norm h3 [b][n][256] -> d_out [b][o][n] ----------------
__global__ __launch_bounds__(256) void gcn_normT(const float* __restrict__ h3,
                                                 const float* __restrict__ mu,
                                                 const float* __restrict__ rs,
                                                 float* __restrict__ out) {
  __shared__ float tile[64][65];
  int x = blockIdx.x;
  int ob = x & 3, nb = (x >> 2) & 63, b = x >> 8;
  int n0 = nb * 64, o0 = ob * 64;
  for (int idx = threadIdx.x; idx < 4096; idx += 256) {
    int nl = idx >> 6, oc = idx & 63;
    tile[nl][oc] = h3[((size_t)(b << 12) + n0 + nl) * 256 + o0 + oc];
  }
  __syncthreads();
  for (int idx = threadIdx.x; idx < 4096; idx += 256) {
    int ol = idx >> 6, nc = idx & 63;
    int t = b * 256 + o0 + ol;
    float v = (tile[nc][ol] - mu[t]) * rs[t];
    v = v > 0.f ? v : 0.2f * v;
    out[((size_t)(b * 256 + o0 + ol) << 12) + n0 + nc] = v;
  }
}

// ---------------- launch ----------------
extern "C" void kernel_launch(void* const* d_in, const int* in_sizes, int n_in,
                              void* d_out, int out_size, void* d_ws, size_t ws_size,
                              hipStream_t stream) {
  (void)in_sizes; (void)n_in; (void)out_size; (void)ws_size;
  const float* coords  = (const float*)d_in[0];
  const float* feats   = (const float*)d_in[1];
  const float* W_lin1  = (const float*)d_in[2];
  const float* b_lin1  = (const float*)d_in[3];
  const float* W_lin2  = (const float*)d_in[4];
  const float* b_lin2  = (const float*)d_in[5];
  const float* W_conv1 = (const float*)d_in[6];
  const float* W_conv2 = (const float*)d_in[7];
  const float* W_conv3 = (const float*)d_in[8];
  char* ws = (char*)d_ws;

  float* F_MM    = (float*)(ws + OFF_MM);
  unsigned long long* KEYS = (unsigned long long*)(ws + OFF_KEYS);
  int* INDS      = (int*)(ws + OFF_INDS);
  _Float16* PK61 = (_Float16*)(ws + OFF_PK6_1);
  _Float16* PK62 = (_Float16*)(ws + OFF_PK6_2);
  _Float16* PK71 = (_Float16*)(ws + OFF_PK7_1);
  _Float16* PK72 = (_Float16*)(ws + OFF_PK7_2);
  float* WFOLD1  = (float*)(ws + OFF_WFOLD1);
  float* WFOLD2  = (float*)(ws + OFF_WFOLD2);
  float* WCOMB1  = (float*)(ws + OFF_WCOMB1);
  float* WCOMB2  = (float*)(ws + OFF_WCOMB2);
  _Float16* PC1  = (_Float16*)(ws + OFF_PC1);
  _Float16* PC2  = (_Float16*)(ws + OFF_PC2);
  float* BC1     = (float*)(ws + OFF_BC1);
  float* BC2     = (float*)(ws + OFF_BC2);
  __half* FEATST = (__half*)(ws + OFF_FEATST);
  __half* F1T    = (__half*)(ws + OFF_F1T);
  __half* F2T    = (__half*)(ws + OFF_F2T);
  float* HMAX1   = (float*)(ws + OFF_HMAX1);
  float* HMAX2   = (float*)(ws + OFF_HMAX2);
  __half* HC1    = (__half*)(ws + OFF_HC1);
  __half* HC2    = (__half*)(ws + OFF_HC2);
  float* S1W     = (float*)(ws + OFF_S1W);
  float* S2W     = (float*)(ws + OFF_S2W);
  _Float16* PF3  = (_Float16*)(ws + OFF_PF3);
  float* H3      = (float*)(ws + OFF_H3);

  // weight prep
  gcn_foldF<<<512, 256, 0, stream>>>(W_lin1, WFOLD1);
  gcn_foldF<<<512, 256, 0, stream>>>(W_lin2, WFOLD2);
  gcn_wcomb<<<256, 256, 0, stream>>>(W_conv1, b_lin1, WFOLD1, WCOMB1, BC1);
  gcn_wcomb<<<512, 256, 0, stream>>>(W_conv2, b_lin2, WFOLD2, WCOMB2, BC2);
  gcn_packC<<<32, 256, 0, stream>>>(WCOMB1, PC1);
  gcn_packC<<<64, 256, 0, stream>>>(WCOMB2, PC2);
  gcn_pack6<<<256, 256, 0, stream>>>(W_lin1, PK61);
  gcn_pack6<<<256, 256, 0, stream>>>(W_lin2, PK62);
  gcn_pack7<<<64,  256, 0, stream>>>(W_conv1, PK71);
  gcn_pack7<<<128, 256, 0, stream>>>(W_conv2, PK72);
  gcn_packF<<<128, 256, 0, stream>>>(W_conv3, PF3);

  // keys + sort + transpose
  gcn_minmax<<<6, 256, 0, stream>>>(coords, F_MM);
  gcn_keys<<<32, 256, 0, stream>>>(coords, F_MM, KEYS);
  gcn_sort<<<8, 1024, 0, stream>>>(KEYS, INDS);
  gcn_transpose<<<2048, 256, 0, stream>>>(feats, FEATST);

  // layer 1 (perm1 = [2,0,3,1])
  gcn_hc<256><<<512, 256, 0, stream>>>(FEATST, PC1, BC1, HC1);
  gcn_window<256><<<2048, 512, 0, stream>>>(
      FEATST, INDS, PK61, PK71, HC1,
      HMAX1, S1W, S2W, 2, 0, 3, 1);
  gcn_stats2<<<512, 256, 0, stream>>>(S1W, S2W,
                                      (float*)(ws + OFF_MU1), (float*)(ws + OFF_RS1),
                                      256, 1024, 1.0f / 40960.0f);
  gcn_norm16<<<8192, 256, 0, stream>>>(HMAX1, (float*)(ws + OFF_MU1), (float*)(ws + OFF_RS1),
                                       F1T, 255, 20);

  // layer 2 (perm2 = [1,3,0,2])
  gcn_hc<512><<<1024, 256, 0, stream>>>(F1T, PC2, BC2, HC2);
  gcn_window<512><<<2048, 512, 0, stream>>>(
      F1T, INDS, PK62, PK72, HC2,
      HMAX2, S1W, S2W, 1, 3, 0, 2);
  gcn_stats2<<<1024, 256, 0, stream>>>(S1W, S2W,
                                       (float*)(ws + OFF_MU2), (float*)(ws + OFF_RS2),
                                       512, 1024, 1.0f / 40960.0f);
  gcn_norm16<<<16384, 256, 0, stream>>>(HMAX2, (float*)(ws + OFF_MU2), (float*)(ws + OFF_RS2),
                                        F2T, 511, 21);

  // final conv (MFMA) + transpose-norm
  gcn_final_mfma<<<512, 256, 0, stream>>>(FEATST, F1T, F2T, PF3,
                                          H3, S1W, S2W);
  gcn_stats2<<<512, 256, 0, stream>>>(S1W, S2W,
                                      (float*)(ws + OFF_MU3), (float*)(ws + OFF_RS3),
                                      256, 256, 1.0f / 4096.0f);
  gcn_normT<<<512, 256, 0, stream>>>(H3, (float*)(ws + OFF_MU3), (float*)(ws + OFF_RS3),
                                     (float*)d_out);
}

// Round 7
// 716.214 us; speedup vs baseline: 1.8947x; 1.1969x over previous
//
#include <hip/hip_runtime.h>
#include <hip/hip_fp16.h>

// =====================================================================
// GCN pipeline on MI355X, round 7:
//  - window: LDS 53120 B (3 blocks/CU even at 2KiB granularity); attn as
//    broadcast half2; window indices live in the 16B/row slab pad; no
//    zero-init (MFMA row-confinement makes garbage rows unread)
//  - window: 8B half4 gathers; P4 attn-apply via __hfma2 (no cvt)
//  - launch fusion: stageA = sort+transpose+folds+packs (sort overlaps
//    prep), stageB = wcomb, stageC = packC
// =====================================================================

typedef _Float16 half8v  __attribute__((ext_vector_type(8)));
typedef _Float16 half4v  __attribute__((ext_vector_type(4)));
typedef float    float4v __attribute__((ext_vector_type(4)));

union H4 { half4v v; __half2 h[2]; };

// ---------------- workspace layout (bytes) ----------------
constexpr size_t OFF_MU1    = 0;
constexpr size_t OFF_RS1    = OFF_MU1 + 2048;
constexpr size_t OFF_MU2    = OFF_RS1 + 2048;
constexpr size_t OFF_RS2    = OFF_MU2 + 4096;
constexpr size_t OFF_MU3    = OFF_RS2 + 4096;
constexpr size_t OFF_RS3    = OFF_MU3 + 2048;
constexpr size_t OFF_MM     = OFF_RS3 + 2048;               // 12 floats
constexpr size_t OFF_KEYS   = OFF_MM + 256;
constexpr size_t OFF_INDS   = OFF_KEYS + 8ull*4096*8;
constexpr size_t OFF_PK6_1  = OFF_INDS + 8ull*4096*10*4;    // 1 MB
constexpr size_t OFF_PK6_2  = OFF_PK6_1 + 512ull*1024*2;
constexpr size_t OFF_PK7_1  = OFF_PK6_2 + 512ull*1024*2;
constexpr size_t OFF_PK7_2  = OFF_PK7_1 + 256ull*512*2;
constexpr size_t OFF_WFOLD1 = OFF_PK7_2 + 512ull*512*2;
constexpr size_t OFF_WFOLD2 = OFF_WFOLD1 + 512ull*256*4;
constexpr size_t OFF_WCOMB1 = OFF_WFOLD2 + 512ull*256*4;
constexpr size_t OFF_WCOMB2 = OFF_WCOMB1 + 256ull*256*4;
constexpr size_t OFF_PC1    = OFF_WCOMB2 + 512ull*256*4;
constexpr size_t OFF_PC2    = OFF_PC1 + 256ull*256*2;
constexpr size_t OFF_BC1    = OFF_PC2 + 512ull*256*2;
constexpr size_t OFF_BC2    = OFF_BC1 + 1024;
constexpr size_t OFF_FEATST = OFF_BC2 + 2048;               // (B,N,256) fp16
constexpr size_t OFF_F1T    = OFF_FEATST + 2ull*4096*256*2; // (B,N,256) fp16
constexpr size_t OFF_F2T    = OFF_F1T   + 2ull*4096*256*2;  // (B,N,512) fp16
constexpr size_t OFF_HMAX1  = OFF_F2T   + 2ull*4096*512*2;  // (B,N,256) fp32
constexpr size_t OFF_HMAX2  = OFF_HMAX1 + 2ull*4096*256*4;  // (B,N,512) fp32
constexpr size_t OFF_HC1    = OFF_HMAX2 + 2ull*4096*512*4;  // fp16 (B*N,256)
constexpr size_t OFF_HC2    = OFF_HC1   + 8192ull*256*2;    // fp16 (B*N,512)
constexpr size_t OFF_S1W    = OFF_HC2   + 8192ull*512*2;    // [2048][<=512] f
constexpr size_t OFF_S2W    = OFF_S1W   + 2048ull*512*4;
constexpr size_t OFF_PF3    = OFF_S2W   + 2048ull*512*4;    // packed Wc3
constexpr size_t WS_NEED    = OFF_PF3   + 256ull*1024*2;
constexpr size_t OFF_H3     = OFF_HMAX1;   // hmax1 dead after norm16-L1

// ---------------- helpers ----------------
__device__ __forceinline__ int gcn_quant1(float c, float cmin, float scale) {
  float q = floorf(__fmul_rn(__fsub_rn(c, cmin), scale));
  q = fminf(fmaxf(q, 0.0f), 1023.0f);
  return (int)q;
}

__device__ __forceinline__ unsigned int gcn_morton3(int x, int y, int z) {
  unsigned int key = 0u;
#pragma unroll
  for (int b = 0; b < 10; ++b) {
    key |= ((unsigned)((x >> b) & 1)) << (3 * b + 2);
    key |= ((unsigned)((y >> b) & 1)) << (3 * b + 1);
    key |= ((unsigned)((z >> b) & 1)) << (3 * b + 0);
  }
  return key;
}

__device__ __forceinline__ unsigned int gcn_hilbert3(int x, int y, int z) {
  int X0 = x, X1 = y, X2 = z;
  for (int Q = 512; Q > 1; Q >>= 1) {
    int P = Q - 1;
    if (X0 & Q) X0 ^= P;
    {
      int t = (X0 ^ X1) & P;
      if (X1 & Q) { X0 ^= P; } else { X0 ^= t; X1 ^= t; }
    }
    {
      int t = (X0 ^ X2) & P;
      if (X2 & Q) { X0 ^= P; } else { X0 ^= t; X2 ^= t; }
    }
  }
  X1 ^= X0;
  X2 ^= X1;
  int t = 0;
  for (int Q = 512; Q > 1; Q >>= 1)
    if (X2 & Q) t ^= (Q - 1);
  X0 ^= t; X1 ^= t; X2 ^= t;
  unsigned int key = 0u;
#pragma unroll
  for (int b = 9; b >= 0; --b) {
    key = (key << 1) | (unsigned)((X0 >> b) & 1);
    key = (key << 1) | (unsigned)((X1 >> b) & 1);
    key = (key << 1) | (unsigned)((X2 >> b) & 1);
  }
  return key;
}

// ---------------- device bodies for fused prep stages ----------------
__device__ void dev_foldF(const float* __restrict__ W, float* __restrict__ Wf, int i) {
  int o = i >> 8, c = i & 255;
  float4 w = ((const float4*)W)[(size_t)o * 512 + c];
  Wf[i] = w.x + w.y + w.z + w.w;
}

__device__ void dev_pack6(const float* __restrict__ W, _Float16* __restrict__ P, int i) {
  int lane = i & 63, ks = (i >> 6) & 31, nt = i >> 11;
  int tl = lane & 15, q = lane >> 4;
  int o = nt * 16 + tl;
  _Float16 tmp[8];
#pragma unroll
  for (int j = 0; j < 8; ++j) {
    int k = ks * 32 + q * 8 + j;
    int hp = k >> 9, r = k & 511, m = r >> 7, cl = r & 127;
    int col = 1024 + 4 * (128 * hp + cl) + m;
    tmp[j] = (_Float16)W[(size_t)o * 2048 + col];
  }
  *(half8v*)(P + (size_t)i * 8) = *(half8v*)tmp;
}

__device__ void dev_pack7(const float* __restrict__ W, _Float16* __restrict__ P, int i) {
  int lane = i & 63, ks = (i >> 6) & 15, nt = i >> 10;
  int tl = lane & 15, q = lane >> 4;
  int o2 = nt * 16 + tl;
  int c2 = ks * 32 + q * 8;
  _Float16 tmp[8];
#pragma unroll
  for (int j = 0; j < 8; ++j)
    tmp[j] = (_Float16)W[(size_t)o2 * 512 + c2 + j];
  *(half8v*)(P + (size_t)i * 8) = *(half8v*)tmp;
}

__device__ void dev_packF(const float* __restrict__ W, _Float16* __restrict__ P, int i) {
  int lane = i & 63, ksg = (i >> 6) & 31, nt = i >> 11;
  int tl = lane & 15, q = lane >> 4;
  int o = nt * 16 + tl;
  _Float16 tmp[8];
#pragma unroll
  for (int j = 0; j < 8; ++j)
    tmp[j] = (_Float16)W[(size_t)o * 1024 + ksg * 32 + q * 8 + j];
  *(half8v*)(P + (size_t)i * 8) = *(half8v*)tmp;
}

__device__ void dev_sort(const unsigned long long* __restrict__ keys,
                         int* __restrict__ inds, int g, int tid,
                         unsigned long long* a) {
  for (int i = tid; i < 4096; i += 1024) a[i] = keys[(size_t)g * 4096 + i];
  __syncthreads();
  for (int k = 2; k <= 4096; k <<= 1) {
    for (int j = k >> 1; j > 0; j >>= 1) {
      for (int t = tid; t < 2048; t += 1024) {
        int i = 2 * t - (t & (j - 1));
        int p = i + j;
        bool up = (i & k) == 0;
        unsigned long long x = a[i], y = a[p];
        if ((x > y) == up) { a[i] = y; a[p] = x; }
      }
      __syncthreads();
    }
  }
  for (int i = tid; i < 4096; i += 1024) {
    int start = i - 5; if (start < 0) start = 0;
    int endm1 = i + 5; if (endm1 > 4095) endm1 = 4095;
#pragma unroll
    for (int kk = 0; kk < 10; ++kk) {
      int pos = start + kk; if (pos > endm1) pos = endm1;
      inds[((size_t)g * 4096 + i) * 10 + kk] = (int)(a[pos] & 0xFFFULL);
    }
  }
}

__device__ void dev_transpose(const float* __restrict__ feats, __half* __restrict__ fT,
                              int vblk, int t256, float* tt) {   // tt: 32*33 floats
  int cb = vblk & 7, nb = (vblk >> 3) & 127, b = vblk >> 10;
  int tx = t256 & 31, ty = t256 >> 5;
#pragma unroll
  for (int i = 0; i < 4; ++i) {
    int c = cb * 32 + ty + i * 8;
    tt[(ty + i * 8) * 33 + tx] = feats[((size_t)(b * 256 + c) << 12) + nb * 32 + tx];
  }
  __syncthreads();
  if (tx < 16) {
#pragma unroll
    for (int i = 0; i < 4; ++i) {
      int nl = ty + i * 8;
      int n = nb * 32 + nl;
      __half2 hv = __floats2half2_rn(tt[(2 * tx) * 33 + nl], tt[(2 * tx + 1) * 33 + nl]);
      *(__half2*)(fT + ((size_t)((b << 12) + n)) * 256 + cb * 32 + 2 * tx) = hv;
    }
  }
}

// ---------------- stage A: sort + transpose + folds + packs (one launch) ----------------
__global__ __launch_bounds__(1024) void gcn_stageA(
    const unsigned long long* __restrict__ keys, int* __restrict__ inds,
    const float* __restrict__ feats, __half* __restrict__ fT,
    const float* __restrict__ W_lin1, const float* __restrict__ W_lin2,
    const float* __restrict__ W_conv1, const float* __restrict__ W_conv2,
    const float* __restrict__ W_conv3,
    float* __restrict__ WFOLD1, float* __restrict__ WFOLD2,
    _Float16* __restrict__ PK61, _Float16* __restrict__ PK62,
    _Float16* __restrict__ PK71, _Float16* __restrict__ PK72,
    _Float16* __restrict__ PF3) {
  __shared__ __align__(16) char smA[32768];
  int blk = blockIdx.x, tid = threadIdx.x;
  if (blk < 8) { dev_sort(keys, inds, blk, tid, (unsigned long long*)smA); return; }
  blk -= 8;
  if (blk < 512) {
    float* tt = (float*)smA + (tid >> 8) * (32 * 33);
    dev_transpose(feats, fT, blk * 4 + (tid >> 8), tid & 255, tt);
    return;
  }
  blk -= 512;
  if (blk < 128) { dev_foldF(W_lin1, WFOLD1, blk * 1024 + tid); return; }
  blk -= 128;
  if (blk < 128) { dev_foldF(W_lin2, WFOLD2, blk * 1024 + tid); return; }
  blk -= 128;
  if (blk < 64)  { dev_pack6(W_lin1, PK61, blk * 1024 + tid); return; }
  blk -= 64;
  if (blk < 64)  { dev_pack6(W_lin2, PK62, blk * 1024 + tid); return; }
  blk -= 64;
  if (blk < 16)  { dev_pack7(W_conv1, PK71, blk * 1024 + tid); return; }
  blk -= 16;
  if (blk < 32)  { dev_pack7(W_conv2, PK72, blk * 1024 + tid); return; }
  blk -= 32;
  dev_packF(W_conv3, PF3, blk * 1024 + tid);
}
constexpr int STAGEA_BLOCKS = 8 + 512 + 128 + 128 + 64 + 64 + 16 + 32 + 32;  // 984

// ---------------- stage B: wcomb (both layers, one launch) ----------------
__device__ void dev_wcomb(const float* __restrict__ Wc, const float* __restrict__ blin,
                          const float* __restrict__ WfoldF, float* __restrict__ Wcomb,
                          float* __restrict__ bc, int o2, float* wrow) {
  int tid = threadIdx.x;
  wrow[tid] = Wc[(size_t)o2 * 512 + tid];
  wrow[tid + 256] = Wc[(size_t)o2 * 512 + tid + 256];
  __syncthreads();
  float acc = 0.f;
  for (int o = 0; o < 512; ++o)
    acc = fmaf(wrow[o], WfoldF[(size_t)o * 256 + tid], acc);
  Wcomb[(size_t)o2 * 256 + tid] = acc;
  if (tid == 0) {
    float s = 0.f;
    for (int o = 0; o < 512; ++o) s += wrow[o] * blin[o];
    bc[o2] = s;
  }
}

__global__ __launch_bounds__(256) void gcn_stageB(
    const float* __restrict__ Wc1, const float* __restrict__ b1,
    const float* __restrict__ Wc2, const float* __restrict__ b2,
    const float* __restrict__ WF1, const float* __restrict__ WF2,
    float* __restrict__ WCOMB1, float* __restrict__ BC1,
    float* __restrict__ WCOMB2, float* __restrict__ BC2) {
  __shared__ float wrow[512];
  int blk = blockIdx.x;
  if (blk < 256) dev_wcomb(Wc1, b1, WF1, WCOMB1, BC1, blk, wrow);
  else           dev_wcomb(Wc2, b2, WF2, WCOMB2, BC2, blk - 256, wrow);
}

// ---------------- stage C: packC (both layers) ----------------
__device__ void dev_packC(const float* __restrict__ Wcomb, _Float16* __restrict__ P, int i) {
  int lane = i & 63, ks = (i >> 6) & 7, nt = i >> 9;
  int tl = lane & 15, q = lane >> 4;
  int n = nt * 16 + tl;
  _Float16 tmp[8];
#pragma unroll
  for (int j = 0; j < 8; ++j)
    tmp[j] = (_Float16)Wcomb[(size_t)n * 256 + ks * 32 + q * 8 + j];
  *(half8v*)(P + (size_t)i * 8) = *(half8v*)tmp;
}

__global__ __launch_bounds__(256) void gcn_stageC(
    const float* __restrict__ WCOMB1, _Float16* __restrict__ PC1,
    const float* __restrict__ WCOMB2, _Float16* __restrict__ PC2) {
  int blk = blockIdx.x;
  if (blk < 32) dev_packC(WCOMB1, PC1, blk * 256 + threadIdx.x);
  else          dev_packC(WCOMB2, PC2, (blk - 32) * 256 + threadIdx.x);
}

// ---------------- hc precompute (fp16 in / fp16 out) ----------------
template <int O2>
__global__ __launch_bounds__(256) void gcn_hc(const __half* __restrict__ src,
                                              const _Float16* __restrict__ PC,
                                              const float* __restrict__ bc,
                                              __half* __restrict__ out) {
  constexpr int NB = O2 / 64;
  __shared__ __align__(16) _Float16 As[64 * 264];
  int nb = blockIdx.x % NB, mb = blockIdx.x / NB;
  int tid = threadIdx.x;
  const __half2* s2 = (const __half2*)(src + (size_t)mb * 64 * 256);
  for (int idx = tid; idx < 64 * 128; idx += 256) {
    int row = idx >> 7, cp = idx & 127;
    __half2 v = s2[row * 128 + cp];
    *(__half2*)((char*)As + row * 528 + cp * 4) = v;
  }
  __syncthreads();
  int lane = tid & 63, w = tid >> 6, tl = lane & 15, q = lane >> 4;
  float4v acc[4];
#pragma unroll
  for (int t = 0; t < 4; ++t) acc[t] = (float4v){0.f, 0.f, 0.f, 0.f};
  const half8v* pc = (const half8v*)PC;
#pragma unroll
  for (int ks = 0; ks < 8; ++ks) {
    half8v a = *(const half8v*)((const char*)As + (w * 16 + tl) * 528 + ks * 64 + q * 16);
#pragma unroll
    for (int t = 0; t < 4; ++t) {
      half8v bf = pc[(size_t)(((nb * 4 + t) * 8 + ks)) * 64 + lane];
      acc[t] = __builtin_amdgcn_mfma_f32_16x16x32_f16(a, bf, acc[t], 0, 0, 0);
    }
  }
#pragma unroll
  for (int t = 0; t < 4; ++t) {
    int o = (nb * 4 + t) * 16 + tl;
    float bb = bc[o];
#pragma unroll
    for (int r = 0; r < 4; ++r) {
      int row = mb * 64 + w * 16 + q * 4 + r;
      out[(size_t)row * O2 + o] = __float2half(acc[t][r] + bb);
    }
  }
}

// ---------------- quantize prep ----------------
__global__ void gcn_minmax(const float* __restrict__ coords, float* __restrict__ mm) {
  __shared__ float slo[256], shi[256];
  int d = blockIdx.x, tid = threadIdx.x;
  float lo = 1e30f, hi = -1e30f;
  for (int i = tid; i < 4096; i += 256) {
    float v = coords[(size_t)d * 4096 + i];
    lo = fminf(lo, v);
    hi = fmaxf(hi, v);
  }
  slo[tid] = lo; shi[tid] = hi;
  __syncthreads();
  for (int s = 128; s > 0; s >>= 1) {
    if (tid < s) {
      slo[tid] = fminf(slo[tid], slo[tid + s]);
      shi[tid] = fmaxf(shi[tid], shi[tid + s]);
    }
    __syncthreads();
  }
  if (tid == 0) {
    mm[d] = slo[0];
    mm[6 + d] = 1023.0f / ((shi[0] - slo[0]) + 1e-6f);
  }
}

__global__ void gcn_keys(const float* __restrict__ coords, const float* __restrict__ mm,
                         unsigned long long* __restrict__ keys) {
  int idx = blockIdx.x * 256 + threadIdx.x;
  int b = idx >> 12, n = idx & 4095;
  const float* cb = coords + (size_t)b * 3 * 4096;
  int q0 = gcn_quant1(cb[n],        mm[b * 3 + 0], mm[6 + b * 3 + 0]);
  int q1 = gcn_quant1(cb[4096 + n], mm[b * 3 + 1], mm[6 + b * 3 + 1]);
  int q2 = gcn_quant1(cb[8192 + n], mm[b * 3 + 2], mm[6 + b * 3 + 2]);
  unsigned long long nn = (unsigned long long)(unsigned)n;
  size_t base = ((size_t)b * 4) * 4096 + n;
  keys[base]         = ((unsigned long long)gcn_morton3(q0, q1, q2) << 12) | nn;
  keys[base + 4096]  = ((unsigned long long)gcn_morton3(q1, q0, q2) << 12) | nn;
  keys[base + 8192]  = ((unsigned long long)gcn_hilbert3(q0, q1, q2) << 12) | nn;
  keys[base + 12288] = ((unsigned long long)gcn_hilbert3(q1, q0, q2) << 12) | nn;
}

// ---------------- fused 4-window MFMA kernel ----------------
// slab/FU: 48 rows x 1040 B at 0 (bytes [0,1024) data, [1024,1040) pad).
// Window indices live in the pads of rows 0..39 (4 ints/row).
// SC: 800 half2 (broadcast attn) at 49920. Total 53120 B -> 3 blocks/CU.
constexpr int ROWB   = 1040;
constexpr int SM_SC  = 49920;
constexpr int SM_TOT = 53120;

__device__ __forceinline__ int& idx_at(char* smem, int j) {
  return ((int*)(smem + (j >> 2) * ROWB + 1024))[j & 3];
}

template <int O2>
__global__ __launch_bounds__(512, 4) void gcn_window(
    const __half* __restrict__ fT, const int* __restrict__ inds,
    const _Float16* __restrict__ PK6, const _Float16* __restrict__ PK7,
    const __half* __restrict__ hc,
    float* __restrict__ hmax, float* __restrict__ S1, float* __restrict__ S2,
    int p0, int p1, int p2, int p3) {
  __shared__ __align__(16) char smem[SM_TOT];
  __half2* sch = (__half2*)(smem + SM_SC);

  const int tid = threadIdx.x;
  const int lane = tid & 63, w = tid >> 6;
  const int tl = lane & 15, q = lane >> 4;
  const int b = blockIdx.x >> 10;
  const int n0 = (blockIdx.x & 1023) * 4;
  const __half* fTb = fT + ((size_t)(b << 12)) * 256;

  // stage window indices into row pads
  if (tid < 160) {
    int g = tid / 40, rem = tid % 40, m = rem / 10, kk = rem % 10;
    int meth = (m == 0) ? p0 : (m == 1) ? p1 : (m == 2) ? p2 : p3;
    idx_at(smem, tid) = inds[((size_t)((b * 4 + meth) << 12) + n0 + g) * 10 + kk];
  }
  __syncthreads();

  float4v acc6[3][4];
#pragma unroll
  for (int mt = 0; mt < 3; ++mt)
#pragma unroll
    for (int t = 0; t < 4; ++t) acc6[mt][t] = (float4v){0.f, 0.f, 0.f, 0.f};

  const half8v* pk6 = (const half8v*)PK6;

#pragma unroll 1
  for (int hp = 0; hp < 2; ++hp) {
    // ---- P1: gather head-pair slab; half4 (8B) per lane; lanes split even/odd kk ----
    {
      const int l32 = lane & 31;
      const int kkh = lane >> 5;
      const int g = w >> 1;
      const half4v cv =
          *(const half4v*)(fTb + (size_t)(n0 + g) * 256 + hp * 128 + 4 * l32);
#pragma unroll
      for (int s = 0; s < 2; ++s) {
        const int m = (w * 2 + s) & 3;
        const int jb = (g * 4 + m) * 10;
#pragma unroll
        for (int kk2 = 0; kk2 < 10; kk2 += 2) {
          int kk = kk2 + kkh;
          int id = idx_at(smem, jb + kk);
          half4v v = *(const half4v*)(fTb + (size_t)id * 256 + hp * 128 + 4 * l32);
          *(half4v*)(smem + (g * 10 + kk) * ROWB + m * 256 + 8 * l32) = v - cv;
        }
      }
    }
    __syncthreads();

    // ---- P2+P3: wave = (window g2, head hh); scores via MFMA + in-wave softmax ----
    {
      int g2 = w >> 1, hh = w & 1;
      float4v as = {0.f, 0.f, 0.f, 0.f};
      const char* rowbase = smem + (g2 * 10 + tl) * ROWB + hh * 128;
#pragma unroll
      for (int m4 = 0; m4 < 4; ++m4) {
        half8v a0 = *(const half8v*)(rowbase + m4 * 256 + q * 16);
        half8v a1 = *(const half8v*)(rowbase + m4 * 256 + 64 + q * 16);
        as = __builtin_amdgcn_mfma_f32_16x16x32_f16(a0, a0, as, 0, 0, 0);
        as = __builtin_amdgcn_mfma_f32_16x16x32_f16(a1, a1, as, 0, 0, 0);
      }
      bool vt = (tl < 10);
      __half2* scb = sch + (g2 * 2 + hh) * 100;
#pragma unroll
      for (int r = 0; r < 4; ++r) {
        float v = vt ? as[r] * 0.0625f : -1e30f;
        float m = v;
        m = fmaxf(m, __shfl_xor(m, 1));
        m = fmaxf(m, __shfl_xor(m, 2));
        m = fmaxf(m, __shfl_xor(m, 4));
        m = fmaxf(m, __shfl_xor(m, 8));
        float e = vt ? __expf(v - m) : 0.f;
        float su = e;
        su += __shfl_xor(su, 1);
        su += __shfl_xor(su, 2);
        su += __shfl_xor(su, 4);
        su += __shfl_xor(su, 8);
        float ar = e / su;
        int row = q * 4 + r;
        if (row < 10 && vt) scb[row * 10 + tl] = __floats2half2_rn(ar, ar);
      }
    }
    __syncthreads();

    // ---- P4: out = attn @ x_diff via __hfma2; thread owns one half4 column ----
    {
      const int g4 = tid >> 7, c4 = tid & 127;
      const __half2* arow = sch + (g4 * 2 + ((c4 >> 4) & 1)) * 100;
      __half2 x0[10], x1[10];
#pragma unroll
      for (int j = 0; j < 10; ++j) {
        H4 u;
        u.v = *(const half4v*)(smem + (g4 * 10 + j) * ROWB + 8 * c4);
        x0[j] = u.h[0];
        x1[j] = u.h[1];
      }
#pragma unroll
      for (int kk = 0; kk < 10; ++kk) {
        __half2 a0 = __floats2half2_rn(0.f, 0.f), a1 = a0;
#pragma unroll
        for (int j = 0; j < 10; ++j) {
          __half2 w2 = arow[kk * 10 + j];
          a0 = __hfma2(w2, x0[j], a0);
          a1 = __hfma2(w2, x1[j], a1);
        }
        H4 o;
        o.h[0] = a0;
        o.h[1] = a1;
        *(half4v*)(smem + (g4 * 10 + kk) * ROWB + 8 * c4) = o.v;
      }
    }
    __syncthreads();

    // ---- P6 partial: acc6 += out_slab @ Wd_slab^T ----
#pragma unroll 2
    for (int ks = 0; ks < 16; ++ks) {
      half8v a0 = *(const half8v*)(smem + (0  + tl) * ROWB + ks * 64 + q * 16);
      half8v a1 = *(const half8v*)(smem + (16 + tl) * ROWB + ks * 64 + q * 16);
      half8v a2 = *(const half8v*)(smem + (32 + tl) * ROWB + ks * 64 + q * 16);
#pragma unroll
      for (int t = 0; t < 4; ++t) {
        half8v bf = pk6[(size_t)(((w * 4 + t) * 32 + hp * 16 + ks)) * 64 + lane];
        acc6[0][t] = __builtin_amdgcn_mfma_f32_16x16x32_f16(a0, bf, acc6[0][t], 0, 0, 0);
        acc6[1][t] = __builtin_amdgcn_mfma_f32_16x16x32_f16(a1, bf, acc6[1][t], 0, 0, 0);
        acc6[2][t] = __builtin_amdgcn_mfma_f32_16x16x32_f16(a2, bf, acc6[2][t], 0, 0, 0);
      }
    }
    __syncthreads();
  }

  // ---- FU write (aliases slab; all P6 reads done) ----
#pragma unroll
  for (int mt = 0; mt < 3; ++mt)
#pragma unroll
    for (int t = 0; t < 4; ++t) {
      int o = (w * 4 + t) * 16 + tl;
#pragma unroll
      for (int r = 0; r < 4; ++r) {
        int row = 16 * mt + q * 4 + r;
        *(__half*)(smem + row * ROWB + o * 2) = __float2half(acc6[mt][t][r]);
      }
    }
  __syncthreads();

  // ---- P7: h = fused @ Wc^T + hc, then max_k + stats ----
  {
    constexpr int NT = O2 / 128;
    float4v acc7[3][NT];
#pragma unroll
    for (int mt = 0; mt < 3; ++mt)
#pragma unroll
      for (int t = 0; t < NT; ++t) acc7[mt][t] = (float4v){0.f, 0.f, 0.f, 0.f};
    const half8v* pk7 = (const half8v*)PK7;
#pragma unroll 2
    for (int ks = 0; ks < 16; ++ks) {
      half8v a0 = *(const half8v*)(smem + (0  + tl) * ROWB + ks * 64 + q * 16);
      half8v a1 = *(const half8v*)(smem + (16 + tl) * ROWB + ks * 64 + q * 16);
      half8v a2 = *(const half8v*)(smem + (32 + tl) * ROWB + ks * 64 + q * 16);
#pragma unroll
      for (int t = 0; t < NT; ++t) {
        half8v bf = pk7[(size_t)(((w * NT + t) * 16 + ks)) * 64 + lane];
        acc7[0][t] = __builtin_amdgcn_mfma_f32_16x16x32_f16(a0, bf, acc7[0][t], 0, 0, 0);
        acc7[1][t] = __builtin_amdgcn_mfma_f32_16x16x32_f16(a1, bf, acc7[1][t], 0, 0, 0);
        acc7[2][t] = __builtin_amdgcn_mfma_f32_16x16x32_f16(a2, bf, acc7[2][t], 0, 0, 0);
      }
    }
#pragma unroll
    for (int t = 0; t < NT; ++t) {
      int o2 = (w * NT + t) * 16 + tl;
      float hcv[4], mx[4], s1[4], s2[4];
#pragma unroll
      for (int g = 0; g < 4; ++g) {
        hcv[g] = __half2float(hc[((size_t)((b << 12) + n0 + g)) * O2 + o2]);
        mx[g] = -1e30f; s1[g] = 0.f; s2[g] = 0.f;
      }
#pragma unroll
      for (int mt = 0; mt < 3; ++mt)
#pragma unroll
        for (int r = 0; r < 4; ++r) {
          int gr = 16 * mt + 4 * q + r;
#pragma unroll
          for (int g = 0; g < 4; ++g) {
            if (gr >= 10 * g && gr < 10 * g + 10) {
              float v = acc7[mt][t][r] + hcv[g];
              mx[g] = fmaxf(mx[g], v);
              s1[g] += v;
              s2[g] = fmaf(v, v, s2[g]);
            }
          }
        }
#pragma unroll
      for (int g = 0; g < 4; ++g) {
        mx[g] = fmaxf(mx[g], __shfl_xor(mx[g], 16));
        mx[g] = fmaxf(mx[g], __shfl_xor(mx[g], 32));
      }
      float s1t = (s1[0] + s1[1]) + (s1[2] + s1[3]);
      float s2t = (s2[0] + s2[1]) + (s2[2] + s2[3]);
      s1t += __shfl_xor(s1t, 16); s1t += __shfl_xor(s1t, 32);
      s2t += __shfl_xor(s2t, 16); s2t += __shfl_xor(s2t, 32);
      if (q == 0) {
#pragma unroll
        for (int g = 0; g < 4; ++g)
          hmax[((size_t)((b << 12) + n0 + g)) * O2 + o2] = mx[g];
        S1[(size_t)blockIdx.x * O2 + o2] = s1t;
        S2[(size_t)blockIdx.x * O2 + o2] = s2t;
      }
    }
  }
}

// ---------------- final conv via MFMA ----------------
__global__ __launch_bounds__(256) void gcn_final_mfma(
    const __half* __restrict__ featsT, const __half* __restrict__ f1T,
    const __half* __restrict__ f2T, const _Float16* __restrict__ PF,
    float* __restrict__ h3, float* __restrict__ S1, float* __restrict__ S2) {
  __shared__ __align__(16) char As[64 * 528];
  const int nb = blockIdx.x & 3, mb = blockIdx.x >> 2;   // mb 0..127
  const int tid = threadIdx.x;
  const int lane = tid & 63, w = tid >> 6, tl = lane & 15, q = lane >> 4;
  const int b = mb >> 6;
  const int nbase = (mb & 63) * 64;
  float4v acc[4];
#pragma unroll
  for (int t = 0; t < 4; ++t) acc[t] = (float4v){0.f, 0.f, 0.f, 0.f};
  const half8v* pf = (const half8v*)PF;
#pragma unroll 1
  for (int kc = 0; kc < 4; ++kc) {
    __syncthreads();
    for (int idx = tid; idx < 64 * 128; idx += 256) {
      int nl = idx >> 7, cp = idx & 127;
      size_t rowg = (size_t)(b << 12) + nbase + nl;
      __half2 v;
      if (kc == 0)      v = *(const __half2*)(featsT + rowg * 256 + cp * 2);
      else if (kc == 1) v = *(const __half2*)(f1T + rowg * 256 + cp * 2);
      else if (kc == 2) v = *(const __half2*)(f2T + rowg * 512 + cp * 2);
      else              v = *(const __half2*)(f2T + rowg * 512 + 256 + cp * 2);
      *(__half2*)(As + nl * 528 + cp * 4) = v;
    }
    __syncthreads();
#pragma unroll
    for (int ks = 0; ks < 8; ++ks) {
      int ksg = kc * 8 + ks;
      half8v a = *(const half8v*)(As + (w * 16 + tl) * 528 + ks * 64 + q * 16);
#pragma unroll
      for (int t = 0; t < 4; ++t) {
        half8v bf = pf[(size_t)(((nb * 4 + t) * 32 + ksg)) * 64 + lane];
        acc[t] = __builtin_amdgcn_mfma_f32_16x16x32_f16(a, bf, acc[t], 0, 0, 0);
      }
    }
  }
#pragma unroll
  for (int t = 0; t < 4; ++t) {
    int o = (nb * 4 + t) * 16 + tl;
    float s1 = 0.f, s2 = 0.f;
#pragma unroll
    for (int r = 0; r < 4; ++r) {
      float v = acc[t][r];
      int n = nbase + w * 16 + q * 4 + r;
      h3[((size_t)(b << 12) + n) * 256 + o] = v;
      s1 += v;
      s2 = fmaf(v, v, s2);
    }
    s1 += __shfl_xor(s1, 16); s1 += __shfl_xor(s1, 32);
    s2 += __shfl_xor(s2, 16); s2 += __shfl_xor(s2, 32);
    if (q == 0) {
      int slot = mb * 4 + w;
      S1[(size_t)slot * 256 + o] = s1;
      S2[(size_t)slot * 256 + o] = s2;
    }
  }
}

// ---------------- stats reduce over nslots block-slots per (b,o2) ----------------
__global__ __launch_bounds__(256) void gcn_stats2(const float* __restrict__ S1,
                                                  const float* __restrict__ S2,
                                                  float* __restrict__ mu,
                                                  float* __restrict__ rs,
                                                  int O2, int nslots, float invNK) {
  __shared__ float r1[256], r2[256];
  int t = blockIdx.x;
  int b = t / O2, o2 = t - b * O2;
  const float* p1 = S1 + (size_t)b * nslots * O2 + o2;
  const float* p2 = S2 + (size_t)b * nslots * O2 + o2;
  float s1 = 0.f, s2 = 0.f;
  for (int i = threadIdx.x; i < nslots; i += 256) {
    s1 += p1[(size_t)i * O2];
    s2 += p2[(size_t)i * O2];
  }
  r1[threadIdx.x] = s1; r2[threadIdx.x] = s2;
  __syncthreads();
  for (int s = 128; s > 0; s >>= 1) {
    if (threadIdx.x < s) {
      r1[threadIdx.x] += r1[threadIdx.x + s];
      r2[threadIdx.x] += r2[threadIdx.x + s];
    }
    __syncthreads();
  }
  if (threadIdx.x == 0) {
    float m = r1[0] * invNK;
    float var = r2[0] * invNK - m * m;
    mu[t] = m;
    rs[t] = 1.0f / sqrtf(var + 1e-5f);
  }
}

// ---------------- normalize + lrelu: hmax [b][n][O2] -> fp16 [b][n][O2] ----------------
__global__ void gcn_norm16(const float* __restrict__ src, const float* __restrict__ mu,
                           const float* __restrict__ rs, __half* __restrict__ out,
                           int omask, int bshift) {
  int idx = blockIdx.x * 256 + threadIdx.x;
  int o = idx & omask;
  int b = idx >> bshift;
  int t = b * (omask + 1) + o;
  float v = (src[idx] - mu[t]) * rs[t];
  v = v > 0.f ? v : 0.2f * v;
  out[idx] = __float2half(v);
}

// ---------------- final: transpose-norm h3 [b][n][256] -> d_out [b][o][n] ----------------
__global__ __launch_bounds__(256) void gcn_normT(const float* __restrict__ h3,
                                                 const float* __restrict__ mu,
                                                 const float* __restrict__ rs,
                                                 float* __restrict__ out) {
  __shared__ float tile[64][65];
  int x = blockIdx.x;
  int ob = x & 3, nb = (x >> 2) & 63, b = x >> 8;
  int n0 = nb * 64, o0 = ob * 64;
  for (int idx = threadIdx.x; idx < 4096; idx += 256) {
    int nl = idx >> 6, oc = idx & 63;
    tile[nl][oc] = h3[((size_t)(b << 12) + n0 + nl) * 256 + o0 + oc];
  }
  __syncthreads();
  for (int idx = threadIdx.x; idx < 4096; idx += 256) {
    int ol = idx >> 6, nc = idx & 63;
    int t = b * 256 + o0 + ol;
    float v = (tile[nc][ol] - mu[t]) * rs[t];
    v = v > 0.f ? v : 0.2f * v;
    out[((size_t)(b * 256 + o0 + ol) << 12) + n0 + nc] = v;
  }
}

// ---------------- launch ----------------
extern "C" void kernel_launch(void* const* d_in, const int* in_sizes, int n_in,
                              void* d_out, int out_size, void* d_ws, size_t ws_size,
                              hipStream_t stream) {
  (void)in_sizes; (void)n_in; (void)out_size; (void)ws_size;
  const float* coords  = (const float*)d_in[0];
  const float* feats   = (const float*)d_in[1];
  const float* W_lin1  = (const float*)d_in[2];
  const float* b_lin1  = (const float*)d_in[3];
  const float* W_lin2  = (const float*)d_in[4];
  const float* b_lin2  = (const float*)d_in[5];
  const float* W_conv1 = (const float*)d_in[6];
  const float* W_conv2 = (const float*)d_in[7];
  const float* W_conv3 = (const float*)d_in[8];
  char* ws = (char*)d_ws;

  float* F_MM    = (float*)(ws + OFF_MM);
  unsigned long long* KEYS = (unsigned long long*)(ws + OFF_KEYS);
  int* INDS      = (int*)(ws + OFF_INDS);
  _Float16* PK61 = (_Float16*)(ws + OFF_PK6_1);
  _Float16* PK62 = (_Float16*)(ws + OFF_PK6_2);
  _Float16* PK71 = (_Float16*)(ws + OFF_PK7_1);
  _Float16* PK72 = (_Float16*)(ws + OFF_PK7_2);
  float* WFOLD1  = (float*)(ws + OFF_WFOLD1);
  float* WFOLD2  = (float*)(ws + OFF_WFOLD2);
  float* WCOMB1  = (float*)(ws + OFF_WCOMB1);
  float* WCOMB2  = (float*)(ws + OFF_WCOMB2);
  _Float16* PC1  = (_Float16*)(ws + OFF_PC1);
  _Float16* PC2  = (_Float16*)(ws + OFF_PC2);
  float* BC1     = (float*)(ws + OFF_BC1);
  float* BC2     = (float*)(ws + OFF_BC2);
  __half* FEATST = (__half*)(ws + OFF_FEATST);
  __half* F1T    = (__half*)(ws + OFF_F1T);
  __half* F2T    = (__half*)(ws + OFF_F2T);
  float* HMAX1   = (float*)(ws + OFF_HMAX1);
  float* HMAX2   = (float*)(ws + OFF_HMAX2);
  __half* HC1    = (__half*)(ws + OFF_HC1);
  __half* HC2    = (__half*)(ws + OFF_HC2);
  float* S1W     = (float*)(ws + OFF_S1W);
  float* S2W     = (float*)(ws + OFF_S2W);
  _Float16* PF3  = (_Float16*)(ws + OFF_PF3);
  float* H3      = (float*)(ws + OFF_H3);

  // keys, then fused prep stages (sort overlaps transpose + weight packs)
  gcn_minmax<<<6, 256, 0, stream>>>(coords, F_MM);
  gcn_keys<<<32, 256, 0, stream>>>(coords, F_MM, KEYS);
  gcn_stageA<<<STAGEA_BLOCKS, 1024, 0, stream>>>(
      KEYS, INDS, feats, FEATST, W_lin1, W_lin2, W_conv1, W_conv2, W_conv3,
      WFOLD1, WFOLD2, PK61, PK62, PK71, PK72, PF3);
  gcn_stageB<<<768, 256, 0, stream>>>(W_conv1, b_lin1, W_conv2, b_lin2,
                                      WFOLD1, WFOLD2, WCOMB1, BC1, WCOMB2, BC2);
  gcn_stageC<<<96, 256, 0, stream>>>(WCOMB1, PC1, WCOMB2, PC2);

  // layer 1 (perm1 = [2,0,3,1])
  gcn_hc<256><<<512, 256, 0, stream>>>(FEATST, PC1, BC1, HC1);
  gcn_window<256><<<2048, 512, 0, stream>>>(
      FEATST, INDS, PK61, PK71, HC1,
      HMAX1, S1W, S2W, 2, 0, 3, 1);
  gcn_stats2<<<512, 256, 0, stream>>>(S1W, S2W,
                                      (float*)(ws + OFF_MU1), (float*)(ws + OFF_RS1),
                                      256, 1024, 1.0f / 40960.0f);
  gcn_norm16<<<8192, 256, 0, stream>>>(HMAX1, (float*)(ws + OFF_MU1), (float*)(ws + OFF_RS1),
                                       F1T, 255, 20);

  // layer 2 (perm2 = [1,3,0,2])
  gcn_hc<512><<<1024, 256, 0, stream>>>(F1T, PC2, BC2, HC2);
  gcn_window<512><<<2048, 512, 0, stream>>>(
      F1T, INDS, PK62, PK72, HC2,
      HMAX2, S1W, S2W, 1, 3, 0, 2);
  gcn_stats2<<<1024, 256, 0, stream>>>(S1W, S2W,
                                       (float*)(ws + OFF_MU2), (float*)(ws + OFF_RS2),
                                       512, 1024, 1.0f / 40960.0f);
  gcn_norm16<<<16384, 256, 0, stream>>>(HMAX2, (float*)(ws + OFF_MU2), (float*)(ws + OFF_RS2),
                                        F2T, 511, 21);

  // final conv (MFMA) + transpose-norm
  gcn_final_mfma<<<512, 256, 0, stream>>>(FEATST, F1T, F2T, PF3, H3, S1W, S2W);
  gcn_stats2<<<512, 256, 0, stream>>>(S1W, S2W,
                                      (float*)(ws + OFF_MU3), (float*)(ws + OFF_RS3),
                                      256, 256, 1.0f / 4096.0f);
  gcn_normT<<<512, 256, 0, stream>>>(H3, (float*)(ws + OFF_MU3), (float*)(ws + OFF_RS3),
                                     (float*)d_out);
}